// Round 4
// baseline (2247.448 us; speedup 1.0000x reference)
//
#include <hip/hip_runtime.h>

// GAT: N=100000 E=1600000 NFEAT=256 NHID=64 NHEADS=4 NCLASS=40 (hardcoded dims).
// r12 (906us): agg1g 244us (occ 58%, LDS 48KB caps 3 blk/CU); k_l2 est ~200us
// latency-bound (edge-serial gather chain); att1 3 gather passes.
// r13: agg1g xs-LDS removed (readlane broadcast tail, bit-exact) -> LDS=40960B
// = 4 blk/CU, launch_bounds(512,8); k_l2 8-edge x 8-class-chunk lane layout
// (8x edge ILP); att1 writes UNNORMALIZED exp + sinv1[n][h], normalization
// folded into agg1g (one mult, distributive). All order-level ~1ulp changes.

#define ALPHA 0.2f
constexpr int N_ = 100000;
constexpr int E_ = 1600000;
constexpr long OUTEL = (long)N_ * 40;

typedef __bf16 bf16x8 __attribute__((ext_vector_type(8)));
typedef float f32x4 __attribute__((ext_vector_type(4)));

__global__ void k_sent(float* out, long n, float v) {
    long i = blockIdx.x * 256L + threadIdx.x;
    if (i < n) out[i] = v;
}

// ---------------- CSR build ----------------

__global__ void k_zero(int* p, int n) {
    int i = blockIdx.x * 256 + threadIdx.x;
    if (i < n) p[i] = 0;
}

__global__ void k_count(const int* __restrict__ dst, int* __restrict__ deg) {
    int e = blockIdx.x * 256 + threadIdx.x;
    if (e < E_) {
        int d = dst[e];
        if ((unsigned)d < (unsigned)N_) atomicAdd(&deg[d], 1);
    }
}

__global__ void k_partial(const int* __restrict__ deg, int* __restrict__ part) {
    __shared__ int sd[256];
    int b = blockIdx.x, t = threadIdx.x;
    int base = b * 1024;
    int s = 0;
    for (int i = 0; i < 4; i++) {
        int idx = base + t * 4 + i;
        if (idx < N_) s += deg[idx];
    }
    sd[t] = s;
    __syncthreads();
    for (int o = 128; o; o >>= 1) {
        if (t < o) sd[t] += sd[t + o];
        __syncthreads();
    }
    if (t == 0) part[b] = sd[0];
}

__global__ void k_scan_part(int* part, int nchunks, int* rowptr) {
    if (threadIdx.x == 0 && blockIdx.x == 0) {
        int run = 0;
        for (int b = 0; b < nchunks; b++) {
            int v = part[b];
            part[b] = run;
            run += v;
        }
        rowptr[N_] = run;
    }
}

__global__ void k_scan_final(const int* __restrict__ deg, const int* __restrict__ part,
                             int* __restrict__ rowptr, int* __restrict__ cursor) {
    __shared__ int sd[256];
    int b = blockIdx.x, t = threadIdx.x;
    int base = b * 1024;
    int v[4];
    int s = 0;
    for (int i = 0; i < 4; i++) {
        int idx = base + t * 4 + i;
        v[i] = (idx < N_) ? deg[idx] : 0;
        s += v[i];
    }
    sd[t] = s;
    __syncthreads();
    for (int o = 1; o < 256; o <<= 1) {
        int add = (t >= o) ? sd[t - o] : 0;
        __syncthreads();
        sd[t] += add;
        __syncthreads();
    }
    int off0 = part[b] + (sd[t] - s);
    for (int i = 0; i < 4; i++) {
        int idx = base + t * 4 + i;
        if (idx < N_) {
            rowptr[idx] = off0;
            cursor[idx] = off0;
            off0 += v[i];
        }
    }
}

__global__ void k_fill(const int* __restrict__ src, const int* __restrict__ dst,
                       int* __restrict__ cursor, int* __restrict__ csr) {
    int e = blockIdx.x * 256 + threadIdx.x;
    if (e < E_) {
        int d = dst[e];
        if ((unsigned)d < (unsigned)N_) {
            int p = atomicAdd(&cursor[d], 1);
            if ((unsigned)p < (unsigned)E_) csr[p] = src[e];
        }
    }
}

// ---------------- B prep: transpose + bf16 hi/lo split + wa columns ----------------

__global__ __launch_bounds__(320) void k_prepB(const float* __restrict__ Whd,
                                               const float* __restrict__ ah,
                                               __bf16* __restrict__ Bh, __bf16* __restrict__ Bl) {
    int k = blockIdx.x;      // 0..255
    int c = threadIdx.x;     // 0..319
    if (c >= 272) return;
    float v = 0.f;
    if (c < 256) {
        v = Whd[(c >> 6) * 16384 + k * 64 + (c & 63)];
    } else if (c < 264) {
        int hh = (c - 256) & 3;
        int isd = (c >= 260) ? 64 : 0;
        const float* wp = Whd + hh * 16384 + k * 64;
        const float* ap = ah + hh * 128 + isd;
        float s = 0.f;
        for (int j = 0; j < 64; j++) s += wp[j] * ap[j];
        v = s;
    }
    __bf16 hi = (__bf16)v;
    __bf16 lo = (__bf16)(v - (float)hi);
    size_t idx = ((size_t)(k >> 5) * 272 + c) * 32 + (k & 31);
    Bh[idx] = hi;
    Bl[idx] = lo;
}

// ---------------- GEMM1 via MFMA 16x16x32 bf16, split-precision (3 terms) ----------------

__global__ __launch_bounds__(256) void k_gemm1m(const float* __restrict__ h,
                                                const __bf16* __restrict__ Bh,
                                                const __bf16* __restrict__ Bl,
                                                float* __restrict__ Wh1,
                                                float* __restrict__ s1s,
                                                float* __restrict__ s1d) {
    int t = threadIdx.x;
    int wv = t >> 6, l = t & 63;
    int l15 = l & 15, lg = l >> 4;
    int rowA = blockIdx.x * 64 + wv * 16 + l15;
    bool rok = rowA < N_;
    const float* hp = h + (size_t)rowA * 256 + lg * 8;

    f32x4 acc[17];
#pragma unroll
    for (int i = 0; i < 17; i++) acc[i] = (f32x4){0.f, 0.f, 0.f, 0.f};

    for (int kc = 0; kc < 8; kc++) {
        float va[8] = {0.f, 0.f, 0.f, 0.f, 0.f, 0.f, 0.f, 0.f};
        if (rok) {
            float4 p = *(const float4*)(hp + kc * 32);
            float4 q = *(const float4*)(hp + kc * 32 + 4);
            va[0] = p.x; va[1] = p.y; va[2] = p.z; va[3] = p.w;
            va[4] = q.x; va[5] = q.y; va[6] = q.z; va[7] = q.w;
        }
        bf16x8 ahi, alo;
#pragma unroll
        for (int j = 0; j < 8; j++) {
            __bf16 hi = (__bf16)va[j];
            ahi[j] = hi;
            alo[j] = (__bf16)(va[j] - (float)hi);
        }
        const __bf16* bph = Bh + ((size_t)kc * 272 + l15) * 32 + lg * 8;
        const __bf16* bpl = Bl + ((size_t)kc * 272 + l15) * 32 + lg * 8;
#pragma unroll
        for (int tt = 0; tt < 17; tt++) {
            bf16x8 bh = *(const bf16x8*)(bph + tt * 512);
            bf16x8 bl = *(const bf16x8*)(bpl + tt * 512);
            acc[tt] = __builtin_amdgcn_mfma_f32_16x16x32_bf16(ahi, bh, acc[tt], 0, 0, 0);
            acc[tt] = __builtin_amdgcn_mfma_f32_16x16x32_bf16(alo, bh, acc[tt], 0, 0, 0);
            acc[tt] = __builtin_amdgcn_mfma_f32_16x16x32_bf16(ahi, bl, acc[tt], 0, 0, 0);
        }
    }

    int rowD0 = blockIdx.x * 64 + wv * 16 + lg * 4;
#pragma unroll
    for (int tt = 0; tt < 16; tt++) {
#pragma unroll
        for (int r = 0; r < 4; r++) {
            int orow = rowD0 + r;
            if (orow < N_) Wh1[(size_t)orow * 256 + tt * 16 + l15] = acc[tt][r];
        }
    }
#pragma unroll
    for (int r = 0; r < 4; r++) {
        int orow = rowD0 + r;
        if (orow < N_) {
            if (l15 < 4) s1s[orow * 4 + l15] = acc[16][r];
            else if (l15 < 8) s1d[orow * 4 + (l15 - 4)] = acc[16][r];
        }
    }
}

// ---------------- att1: 2 gather passes; writes UNNORMALIZED exp + sinv1 ----------------
// 1 wave/node, lane = (edge i = l>>2, head = l&3), 4 nodes/block.

__global__ __launch_bounds__(256) void k_att1(const int* __restrict__ rowptr, const int* __restrict__ csr,
                                              const float* __restrict__ s1s, const float* __restrict__ s1d,
                                              float* __restrict__ att1, float* __restrict__ sinv1) {
    int t = threadIdx.x;
    int wv = t >> 6, l = t & 63;
    int n = blockIdx.x * 4 + wv;
    int base = rowptr[n], deg = rowptr[n + 1] - base;
    int i = l >> 2, hh = l & 3;
    float sdw = s1d[n * 4 + hh];

    float mx = -INFINITY;
    for (int ib = 0; ib < deg; ib += 16) {
        int e = ib + i;
        if (e < deg) {
            int s = csr[base + e];
            float v = s1s[s * 4 + hh] + sdw;
            v = v > 0.f ? v : ALPHA * v;
            mx = fmaxf(mx, v);
        }
    }
    for (int o = 4; o < 64; o <<= 1) mx = fmaxf(mx, __shfl_xor(mx, o));
    float sm = 0.f;
    for (int ib = 0; ib < deg; ib += 16) {
        int e = ib + i;
        if (e < deg) {
            int s = csr[base + e];
            float v = s1s[s * 4 + hh] + sdw;
            v = v > 0.f ? v : ALPHA * v;
            float ex = expf(v - mx);
            att1[(size_t)(base + e) * 4 + hh] = ex;   // unnormalized
            sm += ex;
        }
    }
    for (int o = 4; o < 64; o <<= 1) sm += __shfl_xor(sm, o);
    if (l < 4) sinv1[n * 4 + hh] = (deg > 0) ? 1.f / sm : 0.f;
}

// ---------------- layer-1 aggregate + ELU + GEMM2 + s2 scores, fused, PERSISTENT.
// 1024 blocks (4/CU: LDS exactly 40960B), 8 waves/block, Wo in LDS once/block.
// Tail: readlane broadcast of acc (bit-exact same summation order as xs version).

constexpr int AGG_BLOCKS = 1024;
constexpr int NODES_PER_SWEEP = AGG_BLOCKS * 8;

__global__ __launch_bounds__(512, 8) void k_agg1g(const int* __restrict__ rowptr, const int* __restrict__ csr,
                                                  const float* __restrict__ att1, const float* __restrict__ sinv1,
                                                  const float* __restrict__ Wh1,
                                                  const float* __restrict__ Wo, const float* __restrict__ ao,
                                                  float* __restrict__ Wh2,
                                                  float* __restrict__ s2s, float* __restrict__ s2d) {
    __shared__ float WoS[256 * 40];   // 40960B exactly -> 4 blocks/CU
    int t = threadIdx.x;
#pragma unroll
    for (int u = 0; u < 5; u++) {
        int idx = (u * 512 + t) * 4;
        *(float4*)(&WoS[idx]) = *(const float4*)(&Wo[idx]);
    }
    __syncthreads();

    int w = t >> 6, lane = t & 63;
    int f = lane << 2;
    int hw = lane >> 4;
    int lane40 = (lane < 40) ? lane : 0;   // clamp: lanes>=40 read bank-broadcast, result unused
    float a1 = (lane < 40) ? ao[lane] : 0.f;
    float a2 = (lane < 40) ? ao[40 + lane] : 0.f;

    for (int n = blockIdx.x * 8 + w; n < N_; n += NODES_PER_SWEEP) {
        int base = rowptr[n], deg = rowptr[n + 1] - base;

        float4 acc = make_float4(0.f, 0.f, 0.f, 0.f);
        int i = 0;
        for (; i + 3 < deg; i += 4) {
            int b0 = base + i;
            int s0 = csr[b0], s1 = csr[b0 + 1], s2 = csr[b0 + 2], s3 = csr[b0 + 3];
            float at0 = att1[(size_t)b0 * 4 + hw];
            float at1 = att1[(size_t)(b0 + 1) * 4 + hw];
            float at2 = att1[(size_t)(b0 + 2) * 4 + hw];
            float at3 = att1[(size_t)(b0 + 3) * 4 + hw];
            float4 v0 = *(const float4*)(Wh1 + (size_t)s0 * 256 + f);
            float4 v1 = *(const float4*)(Wh1 + (size_t)s1 * 256 + f);
            float4 v2 = *(const float4*)(Wh1 + (size_t)s2 * 256 + f);
            float4 v3 = *(const float4*)(Wh1 + (size_t)s3 * 256 + f);
            acc.x += at0 * v0.x + at1 * v1.x + at2 * v2.x + at3 * v3.x;
            acc.y += at0 * v0.y + at1 * v1.y + at2 * v2.y + at3 * v3.y;
            acc.z += at0 * v0.z + at1 * v1.z + at2 * v2.z + at3 * v3.z;
            acc.w += at0 * v0.w + at1 * v1.w + at2 * v2.w + at3 * v3.w;
        }
        for (; i < deg; i++) {
            int s0 = csr[base + i];
            float at0 = att1[(size_t)(base + i) * 4 + hw];
            float4 v0 = *(const float4*)(Wh1 + (size_t)s0 * 256 + f);
            acc.x += at0 * v0.x;
            acc.y += at0 * v0.y;
            acc.z += at0 * v0.z;
            acc.w += at0 * v0.w;
        }
        // fold softmax normalization (deferred from att1), then ELU
        float inv = sinv1[n * 4 + hw];
        acc.x *= inv; acc.y *= inv; acc.z *= inv; acc.w *= inv;
        acc.x = acc.x > 0.f ? acc.x : (expf(acc.x) - 1.f);
        acc.y = acc.y > 0.f ? acc.y : (expf(acc.y) - 1.f);
        acc.z = acc.z > 0.f ? acc.z : (expf(acc.z) - 1.f);
        acc.w = acc.w > 0.f ? acc.w : (expf(acc.w) - 1.f);

        // GEMM2 tail: broadcast acc via readlane; x[k=4j+q] lives in lane j comp q.
        float o = 0.f;
#pragma unroll
        for (int j = 0; j < 64; j++) {
            float x0 = __uint_as_float(__builtin_amdgcn_readlane(__float_as_uint(acc.x), j));
            float x1 = __uint_as_float(__builtin_amdgcn_readlane(__float_as_uint(acc.y), j));
            float x2 = __uint_as_float(__builtin_amdgcn_readlane(__float_as_uint(acc.z), j));
            float x3 = __uint_as_float(__builtin_amdgcn_readlane(__float_as_uint(acc.w), j));
            int k4 = j * 4;
            o += x0 * WoS[k4 * 40 + lane40] + x1 * WoS[(k4 + 1) * 40 + lane40] +
                 x2 * WoS[(k4 + 2) * 40 + lane40] + x3 * WoS[(k4 + 3) * 40 + lane40];
        }
        if (lane < 40) Wh2[(size_t)n * 40 + lane] = o;

        float r1 = o * a1, r2 = o * a2;
        for (int off = 32; off; off >>= 1) {
            r1 += __shfl_xor(r1, off);
            r2 += __shfl_xor(r2, off);
        }
        if (lane == 0) {
            s2s[n] = r1;
            s2d[n] = r2;
        }
    }
}

// ---------------- layer-2: att2 inline; aggregate with 8-edge x 8-class-chunk lanes.
// 1 wave/node, 4 nodes/block. lane = e8*8 + c8; c8 owns classes [c8*5, c8*5+5).

__global__ __launch_bounds__(256) void k_l2(const int* __restrict__ rowptr, const int* __restrict__ csr,
                                            const float* __restrict__ s2s, const float* __restrict__ s2d,
                                            const float* __restrict__ Wh2, float* __restrict__ out) {
    int t = threadIdx.x;
    int wv = t >> 6, lane = t & 63;
    int n = blockIdx.x * 4 + wv;
    int base = rowptr[n], deg = rowptr[n + 1] - base;
    float sdw = s2d[n];

    // pass 1: max over edges (64-way)
    float mx = -INFINITY;
    for (int i = lane; i < deg; i += 64) {
        int s = csr[base + i];
        float e = s2s[s] + sdw;
        e = e > 0.f ? e : ALPHA * e;
        mx = fmaxf(mx, e);
    }
    for (int o = 32; o; o >>= 1) mx = fmaxf(mx, __shfl_xor(mx, o));

    // pass 2: 8 edges in flight; each lane accumulates 5 classes
    int e8 = lane >> 3, c8 = lane & 7;
    int cb = c8 * 5;
    float acc0 = 0.f, acc1 = 0.f, acc2 = 0.f, acc3 = 0.f, acc4 = 0.f;
    float smp = 0.f;
    for (int i = e8; i < deg; i += 8) {
        int s = csr[base + i];
        float e = s2s[s] + sdw;
        e = e > 0.f ? e : ALPHA * e;
        float a = expf(e - mx);
        smp += a;
        const float* wp = Wh2 + (size_t)s * 40 + cb;
        acc0 += a * wp[0];
        acc1 += a * wp[1];
        acc2 += a * wp[2];
        acc3 += a * wp[3];
        acc4 += a * wp[4];
    }
    for (int o = 8; o < 64; o <<= 1) {
        smp += __shfl_xor(smp, o);
        acc0 += __shfl_xor(acc0, o);
        acc1 += __shfl_xor(acc1, o);
        acc2 += __shfl_xor(acc2, o);
        acc3 += __shfl_xor(acc3, o);
        acc4 += __shfl_xor(acc4, o);
    }
    float inv = (deg > 0) ? 1.f / smp : 0.f;
    acc0 *= inv; acc1 *= inv; acc2 *= inv; acc3 *= inv; acc4 *= inv;

    // log_softmax over 40 classes (reduce across c8: masks 1,2,4)
    float mv = fmaxf(fmaxf(fmaxf(acc0, acc1), fmaxf(acc2, acc3)), acc4);
    for (int o = 1; o < 8; o <<= 1) mv = fmaxf(mv, __shfl_xor(mv, o));
    float se = expf(acc0 - mv) + expf(acc1 - mv) + expf(acc2 - mv) +
               expf(acc3 - mv) + expf(acc4 - mv);
    for (int o = 1; o < 8; o <<= 1) se += __shfl_xor(se, o);
    float lse = logf(se);
    if (e8 == 0) {
        float* op = out + (size_t)n * 40 + cb;
        op[0] = acc0 - mv - lse;
        op[1] = acc1 - mv - lse;
        op[2] = acc2 - mv - lse;
        op[3] = acc3 - mv - lse;
        op[4] = acc4 - mv - lse;
    }
}

// ---------------- host ----------------

extern "C" void kernel_launch(void* const* d_in, const int* in_sizes, int n_in,
                              void* d_out, int out_size, void* d_ws, size_t ws_size,
                              hipStream_t stream) {
    const float* h   = (const float*)d_in[0];
    const int*   ei  = (const int*)d_in[1];
    const float* Whd = (const float*)d_in[2];
    const float* ah  = (const float*)d_in[3];
    const float* Wo  = (const float*)d_in[4];
    const float* ao  = (const float*)d_in[5];
    float* out = (float*)d_out;

    const int* src = ei;
    const int* dst = ei + E_;
    const int nchunks = (N_ + 1023) / 1024;

    char* ws = (char*)d_ws;
    size_t off = 0;
    auto alloc = [&](size_t bytes) -> char* {
        size_t a = (off + 255) & ~(size_t)255;
        off = a + bytes;
        return ws + a;
    };
    int* rowptr = (int*)alloc((size_t)(N_ + 1) * 4);
    int* cursor = (int*)alloc((size_t)N_ * 4);
    int* deg    = (int*)alloc((size_t)N_ * 4);
    int* part   = (int*)alloc((size_t)(nchunks + 1) * 4);
    int* csr    = (int*)alloc((size_t)E_ * 4);
    float* s1s  = (float*)alloc((size_t)N_ * 4 * 4);
    float* s1d  = (float*)alloc((size_t)N_ * 4 * 4);
    float* sinv1= (float*)alloc((size_t)N_ * 4 * 4);
    float* Wh2  = (float*)alloc((size_t)N_ * 40 * 4);
    float* s2s  = (float*)alloc((size_t)N_ * 4);
    float* s2d  = (float*)alloc((size_t)N_ * 4);
    __bf16* Bh  = (__bf16*)alloc((size_t)8 * 272 * 32 * 2);   // 136 KB
    __bf16* Bl  = (__bf16*)alloc((size_t)8 * 272 * 32 * 2);
    float* att1 = (float*)alloc((size_t)E_ * 4 * 4);   // 25.6 MB
    float* Wh1  = (float*)alloc((size_t)N_ * 256 * 4); // 102.4 MB
    size_t need = off + 256;                            // ~157 MB total

    if (ws_size < need) {
        k_sent<<<(int)((OUTEL + 255) / 256), 256, 0, stream>>>(out, OUTEL, -2.0f);
        return;
    }

    // B prep (independent of CSR)
    k_prepB<<<256, 320, 0, stream>>>(Whd, ah, Bh, Bl);

    // CSR build
    k_zero<<<(N_ + 255) / 256, 256, 0, stream>>>(deg, N_);
    k_count<<<(E_ + 255) / 256, 256, 0, stream>>>(dst, deg);
    k_partial<<<nchunks, 256, 0, stream>>>(deg, part);
    k_scan_part<<<1, 64, 0, stream>>>(part, nchunks, rowptr);
    k_scan_final<<<nchunks, 256, 0, stream>>>(deg, part, rowptr, cursor);
    k_fill<<<(E_ + 255) / 256, 256, 0, stream>>>(src, dst, cursor, csr);

    // layer 1: MFMA GEMM (Wh1 + s1 scores), att1 (2 passes, unnormalized + sinv1)
    k_gemm1m<<<(N_ + 63) / 64, 256, 0, stream>>>(h, Bh, Bl, Wh1, s1s, s1d);
    k_att1<<<N_ / 4, 256, 0, stream>>>(rowptr, csr, s1s, s1d, att1, sinv1);

    // fused aggregate + normalize + ELU + gemm2 + s2 scores (persistent, 4 blk/CU)
    k_agg1g<<<AGG_BLOCKS, 512, 0, stream>>>(rowptr, csr, att1, sinv1, Wh1, Wo, ao, Wh2, s2s, s2d);

    // layer 2 (att2 + denominator fused; 8-edge ILP)
    k_l2<<<N_ / 4, 256, 0, stream>>>(rowptr, csr, s2s, s2d, Wh2, out);
}

// Round 5
// 875.714 us; speedup vs baseline: 2.5664x; 2.5664x over previous
//
#include <hip/hip_runtime.h>

// GAT: N=100000 E=1600000 NFEAT=256 NHID=64 NHEADS=4 NCLASS=40 (hardcoded dims).
// r13 (2247us REGRESSION): launch_bounds(512,8) forced VGPR=32 -> scratch spill
// (FETCH 794MB->3.9GB, WRITE 20->537MB); readlane tail added 2M bank conflicts.
// r14: agg1g reverted to r12 shape (xs-LDS tail, 48KB LDS, 3 blk/CU, NO forced
// min-waves) + 8-edge unroll (2x in-flight gathers) + nontemporal csr/att1 loads
// (keep L2 for Wh1). Kept from r13: sinv1 fold, 2-pass att1, 8-edge-ILP l2.

#define ALPHA 0.2f
constexpr int N_ = 100000;
constexpr int E_ = 1600000;
constexpr long OUTEL = (long)N_ * 40;

typedef __bf16 bf16x8 __attribute__((ext_vector_type(8)));
typedef float f32x4 __attribute__((ext_vector_type(4)));

__global__ void k_sent(float* out, long n, float v) {
    long i = blockIdx.x * 256L + threadIdx.x;
    if (i < n) out[i] = v;
}

// ---------------- CSR build ----------------

__global__ void k_zero(int* p, int n) {
    int i = blockIdx.x * 256 + threadIdx.x;
    if (i < n) p[i] = 0;
}

__global__ void k_count(const int* __restrict__ dst, int* __restrict__ deg) {
    int e = blockIdx.x * 256 + threadIdx.x;
    if (e < E_) {
        int d = dst[e];
        if ((unsigned)d < (unsigned)N_) atomicAdd(&deg[d], 1);
    }
}

__global__ void k_partial(const int* __restrict__ deg, int* __restrict__ part) {
    __shared__ int sd[256];
    int b = blockIdx.x, t = threadIdx.x;
    int base = b * 1024;
    int s = 0;
    for (int i = 0; i < 4; i++) {
        int idx = base + t * 4 + i;
        if (idx < N_) s += deg[idx];
    }
    sd[t] = s;
    __syncthreads();
    for (int o = 128; o; o >>= 1) {
        if (t < o) sd[t] += sd[t + o];
        __syncthreads();
    }
    if (t == 0) part[b] = sd[0];
}

__global__ void k_scan_part(int* part, int nchunks, int* rowptr) {
    if (threadIdx.x == 0 && blockIdx.x == 0) {
        int run = 0;
        for (int b = 0; b < nchunks; b++) {
            int v = part[b];
            part[b] = run;
            run += v;
        }
        rowptr[N_] = run;
    }
}

__global__ void k_scan_final(const int* __restrict__ deg, const int* __restrict__ part,
                             int* __restrict__ rowptr, int* __restrict__ cursor) {
    __shared__ int sd[256];
    int b = blockIdx.x, t = threadIdx.x;
    int base = b * 1024;
    int v[4];
    int s = 0;
    for (int i = 0; i < 4; i++) {
        int idx = base + t * 4 + i;
        v[i] = (idx < N_) ? deg[idx] : 0;
        s += v[i];
    }
    sd[t] = s;
    __syncthreads();
    for (int o = 1; o < 256; o <<= 1) {
        int add = (t >= o) ? sd[t - o] : 0;
        __syncthreads();
        sd[t] += add;
        __syncthreads();
    }
    int off0 = part[b] + (sd[t] - s);
    for (int i = 0; i < 4; i++) {
        int idx = base + t * 4 + i;
        if (idx < N_) {
            rowptr[idx] = off0;
            cursor[idx] = off0;
            off0 += v[i];
        }
    }
}

__global__ void k_fill(const int* __restrict__ src, const int* __restrict__ dst,
                       int* __restrict__ cursor, int* __restrict__ csr) {
    int e = blockIdx.x * 256 + threadIdx.x;
    if (e < E_) {
        int d = dst[e];
        if ((unsigned)d < (unsigned)N_) {
            int p = atomicAdd(&cursor[d], 1);
            if ((unsigned)p < (unsigned)E_) csr[p] = src[e];
        }
    }
}

// ---------------- B prep: transpose + bf16 hi/lo split + wa columns ----------------

__global__ __launch_bounds__(320) void k_prepB(const float* __restrict__ Whd,
                                               const float* __restrict__ ah,
                                               __bf16* __restrict__ Bh, __bf16* __restrict__ Bl) {
    int k = blockIdx.x;      // 0..255
    int c = threadIdx.x;     // 0..319
    if (c >= 272) return;
    float v = 0.f;
    if (c < 256) {
        v = Whd[(c >> 6) * 16384 + k * 64 + (c & 63)];
    } else if (c < 264) {
        int hh = (c - 256) & 3;
        int isd = (c >= 260) ? 64 : 0;
        const float* wp = Whd + hh * 16384 + k * 64;
        const float* ap = ah + hh * 128 + isd;
        float s = 0.f;
        for (int j = 0; j < 64; j++) s += wp[j] * ap[j];
        v = s;
    }
    __bf16 hi = (__bf16)v;
    __bf16 lo = (__bf16)(v - (float)hi);
    size_t idx = ((size_t)(k >> 5) * 272 + c) * 32 + (k & 31);
    Bh[idx] = hi;
    Bl[idx] = lo;
}

// ---------------- GEMM1 via MFMA 16x16x32 bf16, split-precision (3 terms) ----------------

__global__ __launch_bounds__(256) void k_gemm1m(const float* __restrict__ h,
                                                const __bf16* __restrict__ Bh,
                                                const __bf16* __restrict__ Bl,
                                                float* __restrict__ Wh1,
                                                float* __restrict__ s1s,
                                                float* __restrict__ s1d) {
    int t = threadIdx.x;
    int wv = t >> 6, l = t & 63;
    int l15 = l & 15, lg = l >> 4;
    int rowA = blockIdx.x * 64 + wv * 16 + l15;
    bool rok = rowA < N_;
    const float* hp = h + (size_t)rowA * 256 + lg * 8;

    f32x4 acc[17];
#pragma unroll
    for (int i = 0; i < 17; i++) acc[i] = (f32x4){0.f, 0.f, 0.f, 0.f};

    for (int kc = 0; kc < 8; kc++) {
        float va[8] = {0.f, 0.f, 0.f, 0.f, 0.f, 0.f, 0.f, 0.f};
        if (rok) {
            float4 p = *(const float4*)(hp + kc * 32);
            float4 q = *(const float4*)(hp + kc * 32 + 4);
            va[0] = p.x; va[1] = p.y; va[2] = p.z; va[3] = p.w;
            va[4] = q.x; va[5] = q.y; va[6] = q.z; va[7] = q.w;
        }
        bf16x8 ahi, alo;
#pragma unroll
        for (int j = 0; j < 8; j++) {
            __bf16 hi = (__bf16)va[j];
            ahi[j] = hi;
            alo[j] = (__bf16)(va[j] - (float)hi);
        }
        const __bf16* bph = Bh + ((size_t)kc * 272 + l15) * 32 + lg * 8;
        const __bf16* bpl = Bl + ((size_t)kc * 272 + l15) * 32 + lg * 8;
#pragma unroll
        for (int tt = 0; tt < 17; tt++) {
            bf16x8 bh = *(const bf16x8*)(bph + tt * 512);
            bf16x8 bl = *(const bf16x8*)(bpl + tt * 512);
            acc[tt] = __builtin_amdgcn_mfma_f32_16x16x32_bf16(ahi, bh, acc[tt], 0, 0, 0);
            acc[tt] = __builtin_amdgcn_mfma_f32_16x16x32_bf16(alo, bh, acc[tt], 0, 0, 0);
            acc[tt] = __builtin_amdgcn_mfma_f32_16x16x32_bf16(ahi, bl, acc[tt], 0, 0, 0);
        }
    }

    int rowD0 = blockIdx.x * 64 + wv * 16 + lg * 4;
#pragma unroll
    for (int tt = 0; tt < 16; tt++) {
#pragma unroll
        for (int r = 0; r < 4; r++) {
            int orow = rowD0 + r;
            if (orow < N_) Wh1[(size_t)orow * 256 + tt * 16 + l15] = acc[tt][r];
        }
    }
#pragma unroll
    for (int r = 0; r < 4; r++) {
        int orow = rowD0 + r;
        if (orow < N_) {
            if (l15 < 4) s1s[orow * 4 + l15] = acc[16][r];
            else if (l15 < 8) s1d[orow * 4 + (l15 - 4)] = acc[16][r];
        }
    }
}

// ---------------- att1: 2 gather passes; writes UNNORMALIZED exp + sinv1 ----------------

__global__ __launch_bounds__(256) void k_att1(const int* __restrict__ rowptr, const int* __restrict__ csr,
                                              const float* __restrict__ s1s, const float* __restrict__ s1d,
                                              float* __restrict__ att1, float* __restrict__ sinv1) {
    int t = threadIdx.x;
    int wv = t >> 6, l = t & 63;
    int n = blockIdx.x * 4 + wv;
    int base = rowptr[n], deg = rowptr[n + 1] - base;
    int i = l >> 2, hh = l & 3;
    float sdw = s1d[n * 4 + hh];

    float mx = -INFINITY;
    for (int ib = 0; ib < deg; ib += 16) {
        int e = ib + i;
        if (e < deg) {
            int s = csr[base + e];
            float v = s1s[s * 4 + hh] + sdw;
            v = v > 0.f ? v : ALPHA * v;
            mx = fmaxf(mx, v);
        }
    }
    for (int o = 4; o < 64; o <<= 1) mx = fmaxf(mx, __shfl_xor(mx, o));
    float sm = 0.f;
    for (int ib = 0; ib < deg; ib += 16) {
        int e = ib + i;
        if (e < deg) {
            int s = csr[base + e];
            float v = s1s[s * 4 + hh] + sdw;
            v = v > 0.f ? v : ALPHA * v;
            float ex = expf(v - mx);
            att1[(size_t)(base + e) * 4 + hh] = ex;   // unnormalized
            sm += ex;
        }
    }
    for (int o = 4; o < 64; o <<= 1) sm += __shfl_xor(sm, o);
    if (l < 4) sinv1[n * 4 + hh] = (deg > 0) ? 1.f / sm : 0.f;
}

// ---------------- layer-1 aggregate + normalize + ELU + GEMM2 + s2 scores, fused,
// PERSISTENT. 768 blocks (3/CU, 48KB LDS), 8 waves/block, Wo in LDS once/block.
// 8-edge unroll gather; csr/att1 via nontemporal loads (keep L2 for Wh1).
// NO forced min-waves (r13 lesson: spills). Tail via wave-private xs LDS.

constexpr int AGG_BLOCKS = 768;
constexpr int NODES_PER_SWEEP = AGG_BLOCKS * 8;

__global__ __launch_bounds__(512) void k_agg1g(const int* __restrict__ rowptr, const int* __restrict__ csr,
                                               const float* __restrict__ att1, const float* __restrict__ sinv1,
                                               const float* __restrict__ Wh1,
                                               const float* __restrict__ Wo, const float* __restrict__ ao,
                                               float* __restrict__ Wh2,
                                               float* __restrict__ s2s, float* __restrict__ s2d) {
    __shared__ float WoS[256 * 40];
    __shared__ float xs[8][256];
    int t = threadIdx.x;
#pragma unroll
    for (int u = 0; u < 5; u++) {
        int idx = (u * 512 + t) * 4;
        *(float4*)(&WoS[idx]) = *(const float4*)(&Wo[idx]);
    }
    __syncthreads();

    int w = t >> 6, lane = t & 63;
    int f = lane << 2;
    int hw = lane >> 4;
    float a1 = (lane < 40) ? ao[lane] : 0.f;
    float a2 = (lane < 40) ? ao[40 + lane] : 0.f;

    for (int n = blockIdx.x * 8 + w; n < N_; n += NODES_PER_SWEEP) {
        int base = rowptr[n], deg = rowptr[n + 1] - base;

        float4 acc = make_float4(0.f, 0.f, 0.f, 0.f);
        int i = 0;
        for (; i + 7 < deg; i += 8) {
            int b0 = base + i;
            int s[8];
            float at[8];
#pragma unroll
            for (int u = 0; u < 8; u++) {
                s[u] = __builtin_nontemporal_load(csr + b0 + u);
                at[u] = __builtin_nontemporal_load(att1 + (size_t)(b0 + u) * 4 + hw);
            }
            float4 v[8];
#pragma unroll
            for (int u = 0; u < 8; u++) v[u] = *(const float4*)(Wh1 + (size_t)s[u] * 256 + f);
#pragma unroll
            for (int u = 0; u < 8; u++) {
                acc.x += at[u] * v[u].x;
                acc.y += at[u] * v[u].y;
                acc.z += at[u] * v[u].z;
                acc.w += at[u] * v[u].w;
            }
        }
        for (; i + 3 < deg; i += 4) {
            int b0 = base + i;
            int s0 = csr[b0], s1 = csr[b0 + 1], s2 = csr[b0 + 2], s3 = csr[b0 + 3];
            float at0 = att1[(size_t)b0 * 4 + hw];
            float at1 = att1[(size_t)(b0 + 1) * 4 + hw];
            float at2 = att1[(size_t)(b0 + 2) * 4 + hw];
            float at3 = att1[(size_t)(b0 + 3) * 4 + hw];
            float4 v0 = *(const float4*)(Wh1 + (size_t)s0 * 256 + f);
            float4 v1 = *(const float4*)(Wh1 + (size_t)s1 * 256 + f);
            float4 v2 = *(const float4*)(Wh1 + (size_t)s2 * 256 + f);
            float4 v3 = *(const float4*)(Wh1 + (size_t)s3 * 256 + f);
            acc.x += at0 * v0.x + at1 * v1.x + at2 * v2.x + at3 * v3.x;
            acc.y += at0 * v0.y + at1 * v1.y + at2 * v2.y + at3 * v3.y;
            acc.z += at0 * v0.z + at1 * v1.z + at2 * v2.z + at3 * v3.z;
            acc.w += at0 * v0.w + at1 * v1.w + at2 * v2.w + at3 * v3.w;
        }
        for (; i < deg; i++) {
            int s0 = csr[base + i];
            float at0 = att1[(size_t)(base + i) * 4 + hw];
            float4 v0 = *(const float4*)(Wh1 + (size_t)s0 * 256 + f);
            acc.x += at0 * v0.x;
            acc.y += at0 * v0.y;
            acc.z += at0 * v0.z;
            acc.w += at0 * v0.w;
        }
        // fold softmax normalization (deferred from att1), then ELU
        float inv = sinv1[n * 4 + hw];
        acc.x *= inv; acc.y *= inv; acc.z *= inv; acc.w *= inv;
        acc.x = acc.x > 0.f ? acc.x : (expf(acc.x) - 1.f);
        acc.y = acc.y > 0.f ? acc.y : (expf(acc.y) - 1.f);
        acc.z = acc.z > 0.f ? acc.z : (expf(acc.z) - 1.f);
        acc.w = acc.w > 0.f ? acc.w : (expf(acc.w) - 1.f);
        *(float4*)(&xs[w][f]) = acc;
        // wave-private LDS RAW: compiler inserts lgkmcnt wait; no barrier needed.

        // GEMM2 tail: lanes 0..39 compute Wh2[n][c]; xs reads are wave-uniform broadcast.
        float o = 0.f;
        if (lane < 40) {
            for (int k = 0; k < 256; k += 4) {
                float4 xk = *(const float4*)(&xs[w][k]);
                o += xk.x * WoS[k * 40 + lane] + xk.y * WoS[(k + 1) * 40 + lane] +
                     xk.z * WoS[(k + 2) * 40 + lane] + xk.w * WoS[(k + 3) * 40 + lane];
            }
            Wh2[(size_t)n * 40 + lane] = o;
        }
        float r1 = o * a1, r2 = o * a2;
        for (int off = 32; off; off >>= 1) {
            r1 += __shfl_xor(r1, off);
            r2 += __shfl_xor(r2, off);
        }
        if (lane == 0) {
            s2s[n] = r1;
            s2d[n] = r2;
        }
    }
}

// ---------------- layer-2: att2 inline; aggregate with 8-edge x 8-class-chunk lanes ----------------

__global__ __launch_bounds__(256) void k_l2(const int* __restrict__ rowptr, const int* __restrict__ csr,
                                            const float* __restrict__ s2s, const float* __restrict__ s2d,
                                            const float* __restrict__ Wh2, float* __restrict__ out) {
    int t = threadIdx.x;
    int wv = t >> 6, lane = t & 63;
    int n = blockIdx.x * 4 + wv;
    int base = rowptr[n], deg = rowptr[n + 1] - base;
    float sdw = s2d[n];

    // pass 1: max over edges (64-way)
    float mx = -INFINITY;
    for (int i = lane; i < deg; i += 64) {
        int s = csr[base + i];
        float e = s2s[s] + sdw;
        e = e > 0.f ? e : ALPHA * e;
        mx = fmaxf(mx, e);
    }
    for (int o = 32; o; o >>= 1) mx = fmaxf(mx, __shfl_xor(mx, o));

    // pass 2: 8 edges in flight; each lane accumulates 5 classes
    int e8 = lane >> 3, c8 = lane & 7;
    int cb = c8 * 5;
    float acc0 = 0.f, acc1 = 0.f, acc2 = 0.f, acc3 = 0.f, acc4 = 0.f;
    float smp = 0.f;
    for (int i = e8; i < deg; i += 8) {
        int s = csr[base + i];
        float e = s2s[s] + sdw;
        e = e > 0.f ? e : ALPHA * e;
        float a = expf(e - mx);
        smp += a;
        const float* wp = Wh2 + (size_t)s * 40 + cb;
        acc0 += a * wp[0];
        acc1 += a * wp[1];
        acc2 += a * wp[2];
        acc3 += a * wp[3];
        acc4 += a * wp[4];
    }
    for (int o = 8; o < 64; o <<= 1) {
        smp += __shfl_xor(smp, o);
        acc0 += __shfl_xor(acc0, o);
        acc1 += __shfl_xor(acc1, o);
        acc2 += __shfl_xor(acc2, o);
        acc3 += __shfl_xor(acc3, o);
        acc4 += __shfl_xor(acc4, o);
    }
    float inv = (deg > 0) ? 1.f / smp : 0.f;
    acc0 *= inv; acc1 *= inv; acc2 *= inv; acc3 *= inv; acc4 *= inv;

    // log_softmax over 40 classes (reduce across c8: masks 1,2,4)
    float mv = fmaxf(fmaxf(fmaxf(acc0, acc1), fmaxf(acc2, acc3)), acc4);
    for (int o = 1; o < 8; o <<= 1) mv = fmaxf(mv, __shfl_xor(mv, o));
    float se = expf(acc0 - mv) + expf(acc1 - mv) + expf(acc2 - mv) +
               expf(acc3 - mv) + expf(acc4 - mv);
    for (int o = 1; o < 8; o <<= 1) se += __shfl_xor(se, o);
    float lse = logf(se);
    if (e8 == 0) {
        float* op = out + (size_t)n * 40 + cb;
        op[0] = acc0 - mv - lse;
        op[1] = acc1 - mv - lse;
        op[2] = acc2 - mv - lse;
        op[3] = acc3 - mv - lse;
        op[4] = acc4 - mv - lse;
    }
}

// ---------------- host ----------------

extern "C" void kernel_launch(void* const* d_in, const int* in_sizes, int n_in,
                              void* d_out, int out_size, void* d_ws, size_t ws_size,
                              hipStream_t stream) {
    const float* h   = (const float*)d_in[0];
    const int*   ei  = (const int*)d_in[1];
    const float* Whd = (const float*)d_in[2];
    const float* ah  = (const float*)d_in[3];
    const float* Wo  = (const float*)d_in[4];
    const float* ao  = (const float*)d_in[5];
    float* out = (float*)d_out;

    const int* src = ei;
    const int* dst = ei + E_;
    const int nchunks = (N_ + 1023) / 1024;

    char* ws = (char*)d_ws;
    size_t off = 0;
    auto alloc = [&](size_t bytes) -> char* {
        size_t a = (off + 255) & ~(size_t)255;
        off = a + bytes;
        return ws + a;
    };
    int* rowptr = (int*)alloc((size_t)(N_ + 1) * 4);
    int* cursor = (int*)alloc((size_t)N_ * 4);
    int* deg    = (int*)alloc((size_t)N_ * 4);
    int* part   = (int*)alloc((size_t)(nchunks + 1) * 4);
    int* csr    = (int*)alloc((size_t)E_ * 4);
    float* s1s  = (float*)alloc((size_t)N_ * 4 * 4);
    float* s1d  = (float*)alloc((size_t)N_ * 4 * 4);
    float* sinv1= (float*)alloc((size_t)N_ * 4 * 4);
    float* Wh2  = (float*)alloc((size_t)N_ * 40 * 4);
    float* s2s  = (float*)alloc((size_t)N_ * 4);
    float* s2d  = (float*)alloc((size_t)N_ * 4);
    __bf16* Bh  = (__bf16*)alloc((size_t)8 * 272 * 32 * 2);   // 136 KB
    __bf16* Bl  = (__bf16*)alloc((size_t)8 * 272 * 32 * 2);
    float* att1 = (float*)alloc((size_t)E_ * 4 * 4);   // 25.6 MB
    float* Wh1  = (float*)alloc((size_t)N_ * 256 * 4); // 102.4 MB
    size_t need = off + 256;                            // ~157 MB total

    if (ws_size < need) {
        k_sent<<<(int)((OUTEL + 255) / 256), 256, 0, stream>>>(out, OUTEL, -2.0f);
        return;
    }

    // B prep (independent of CSR)
    k_prepB<<<256, 320, 0, stream>>>(Whd, ah, Bh, Bl);

    // CSR build
    k_zero<<<(N_ + 255) / 256, 256, 0, stream>>>(deg, N_);
    k_count<<<(E_ + 255) / 256, 256, 0, stream>>>(dst, deg);
    k_partial<<<nchunks, 256, 0, stream>>>(deg, part);
    k_scan_part<<<1, 64, 0, stream>>>(part, nchunks, rowptr);
    k_scan_final<<<nchunks, 256, 0, stream>>>(deg, part, rowptr, cursor);
    k_fill<<<(E_ + 255) / 256, 256, 0, stream>>>(src, dst, cursor, csr);

    // layer 1: MFMA GEMM (Wh1 + s1 scores), att1 (2 passes, unnormalized + sinv1)
    k_gemm1m<<<(N_ + 63) / 64, 256, 0, stream>>>(h, Bh, Bl, Wh1, s1s, s1d);
    k_att1<<<N_ / 4, 256, 0, stream>>>(rowptr, csr, s1s, s1d, att1, sinv1);

    // fused aggregate + normalize + ELU + gemm2 + s2 scores (persistent, 3 blk/CU)
    k_agg1g<<<AGG_BLOCKS, 512, 0, stream>>>(rowptr, csr, att1, sinv1, Wh1, Wo, ao, Wh2, s2s, s2d);

    // layer 2 (att2 + denominator fused; 8-edge ILP)
    k_l2<<<N_ / 4, 256, 0, stream>>>(rowptr, csr, s2s, s2d, Wh2, out);
}

// Round 6
// 863.356 us; speedup vs baseline: 2.6032x; 1.0143x over previous
//
#include <hip/hip_runtime.h>

// GAT: N=100000 E=1600000 NFEAT=256 NHID=64 NHEADS=4 NCLASS=40 (hardcoded dims).
// r14 (875us): agg1g 299us — 8-unroll+nontemporal BOTH hurt (occ 31%, 2.83TB/s);
// revert to r12 4-unroll. Non-agg kernels stable ~576us.
// r15: agg1g occupancy 3->4 blocks/CU: drop xs LDS, GEMM2 tail via readlane
// broadcast (bit-exact same summation order), LDS = 40960B exactly, grid 1024,
// natural VGPR (NO forced min-waves — r13 spill lesson). k_l2: interleaved
// class mapping c=c8+8q -> Wh2 row reads coalesce (5x32B vs 40x4B per edge).

#define ALPHA 0.2f
constexpr int N_ = 100000;
constexpr int E_ = 1600000;
constexpr long OUTEL = (long)N_ * 40;

typedef __bf16 bf16x8 __attribute__((ext_vector_type(8)));
typedef float f32x4 __attribute__((ext_vector_type(4)));

__global__ void k_sent(float* out, long n, float v) {
    long i = blockIdx.x * 256L + threadIdx.x;
    if (i < n) out[i] = v;
}

// ---------------- CSR build ----------------

__global__ void k_zero(int* p, int n) {
    int i = blockIdx.x * 256 + threadIdx.x;
    if (i < n) p[i] = 0;
}

__global__ void k_count(const int* __restrict__ dst, int* __restrict__ deg) {
    int e = blockIdx.x * 256 + threadIdx.x;
    if (e < E_) {
        int d = dst[e];
        if ((unsigned)d < (unsigned)N_) atomicAdd(&deg[d], 1);
    }
}

__global__ void k_partial(const int* __restrict__ deg, int* __restrict__ part) {
    __shared__ int sd[256];
    int b = blockIdx.x, t = threadIdx.x;
    int base = b * 1024;
    int s = 0;
    for (int i = 0; i < 4; i++) {
        int idx = base + t * 4 + i;
        if (idx < N_) s += deg[idx];
    }
    sd[t] = s;
    __syncthreads();
    for (int o = 128; o; o >>= 1) {
        if (t < o) sd[t] += sd[t + o];
        __syncthreads();
    }
    if (t == 0) part[b] = sd[0];
}

__global__ void k_scan_part(int* part, int nchunks, int* rowptr) {
    if (threadIdx.x == 0 && blockIdx.x == 0) {
        int run = 0;
        for (int b = 0; b < nchunks; b++) {
            int v = part[b];
            part[b] = run;
            run += v;
        }
        rowptr[N_] = run;
    }
}

__global__ void k_scan_final(const int* __restrict__ deg, const int* __restrict__ part,
                             int* __restrict__ rowptr, int* __restrict__ cursor) {
    __shared__ int sd[256];
    int b = blockIdx.x, t = threadIdx.x;
    int base = b * 1024;
    int v[4];
    int s = 0;
    for (int i = 0; i < 4; i++) {
        int idx = base + t * 4 + i;
        v[i] = (idx < N_) ? deg[idx] : 0;
        s += v[i];
    }
    sd[t] = s;
    __syncthreads();
    for (int o = 1; o < 256; o <<= 1) {
        int add = (t >= o) ? sd[t - o] : 0;
        __syncthreads();
        sd[t] += add;
        __syncthreads();
    }
    int off0 = part[b] + (sd[t] - s);
    for (int i = 0; i < 4; i++) {
        int idx = base + t * 4 + i;
        if (idx < N_) {
            rowptr[idx] = off0;
            cursor[idx] = off0;
            off0 += v[i];
        }
    }
}

__global__ void k_fill(const int* __restrict__ src, const int* __restrict__ dst,
                       int* __restrict__ cursor, int* __restrict__ csr) {
    int e = blockIdx.x * 256 + threadIdx.x;
    if (e < E_) {
        int d = dst[e];
        if ((unsigned)d < (unsigned)N_) {
            int p = atomicAdd(&cursor[d], 1);
            if ((unsigned)p < (unsigned)E_) csr[p] = src[e];
        }
    }
}

// ---------------- B prep: transpose + bf16 hi/lo split + wa columns ----------------

__global__ __launch_bounds__(320) void k_prepB(const float* __restrict__ Whd,
                                               const float* __restrict__ ah,
                                               __bf16* __restrict__ Bh, __bf16* __restrict__ Bl) {
    int k = blockIdx.x;      // 0..255
    int c = threadIdx.x;     // 0..319
    if (c >= 272) return;
    float v = 0.f;
    if (c < 256) {
        v = Whd[(c >> 6) * 16384 + k * 64 + (c & 63)];
    } else if (c < 264) {
        int hh = (c - 256) & 3;
        int isd = (c >= 260) ? 64 : 0;
        const float* wp = Whd + hh * 16384 + k * 64;
        const float* ap = ah + hh * 128 + isd;
        float s = 0.f;
        for (int j = 0; j < 64; j++) s += wp[j] * ap[j];
        v = s;
    }
    __bf16 hi = (__bf16)v;
    __bf16 lo = (__bf16)(v - (float)hi);
    size_t idx = ((size_t)(k >> 5) * 272 + c) * 32 + (k & 31);
    Bh[idx] = hi;
    Bl[idx] = lo;
}

// ---------------- GEMM1 via MFMA 16x16x32 bf16, split-precision (3 terms) ----------------

__global__ __launch_bounds__(256) void k_gemm1m(const float* __restrict__ h,
                                                const __bf16* __restrict__ Bh,
                                                const __bf16* __restrict__ Bl,
                                                float* __restrict__ Wh1,
                                                float* __restrict__ s1s,
                                                float* __restrict__ s1d) {
    int t = threadIdx.x;
    int wv = t >> 6, l = t & 63;
    int l15 = l & 15, lg = l >> 4;
    int rowA = blockIdx.x * 64 + wv * 16 + l15;
    bool rok = rowA < N_;
    const float* hp = h + (size_t)rowA * 256 + lg * 8;

    f32x4 acc[17];
#pragma unroll
    for (int i = 0; i < 17; i++) acc[i] = (f32x4){0.f, 0.f, 0.f, 0.f};

    for (int kc = 0; kc < 8; kc++) {
        float va[8] = {0.f, 0.f, 0.f, 0.f, 0.f, 0.f, 0.f, 0.f};
        if (rok) {
            float4 p = *(const float4*)(hp + kc * 32);
            float4 q = *(const float4*)(hp + kc * 32 + 4);
            va[0] = p.x; va[1] = p.y; va[2] = p.z; va[3] = p.w;
            va[4] = q.x; va[5] = q.y; va[6] = q.z; va[7] = q.w;
        }
        bf16x8 ahi, alo;
#pragma unroll
        for (int j = 0; j < 8; j++) {
            __bf16 hi = (__bf16)va[j];
            ahi[j] = hi;
            alo[j] = (__bf16)(va[j] - (float)hi);
        }
        const __bf16* bph = Bh + ((size_t)kc * 272 + l15) * 32 + lg * 8;
        const __bf16* bpl = Bl + ((size_t)kc * 272 + l15) * 32 + lg * 8;
#pragma unroll
        for (int tt = 0; tt < 17; tt++) {
            bf16x8 bh = *(const bf16x8*)(bph + tt * 512);
            bf16x8 bl = *(const bf16x8*)(bpl + tt * 512);
            acc[tt] = __builtin_amdgcn_mfma_f32_16x16x32_bf16(ahi, bh, acc[tt], 0, 0, 0);
            acc[tt] = __builtin_amdgcn_mfma_f32_16x16x32_bf16(alo, bh, acc[tt], 0, 0, 0);
            acc[tt] = __builtin_amdgcn_mfma_f32_16x16x32_bf16(ahi, bl, acc[tt], 0, 0, 0);
        }
    }

    int rowD0 = blockIdx.x * 64 + wv * 16 + lg * 4;
#pragma unroll
    for (int tt = 0; tt < 16; tt++) {
#pragma unroll
        for (int r = 0; r < 4; r++) {
            int orow = rowD0 + r;
            if (orow < N_) Wh1[(size_t)orow * 256 + tt * 16 + l15] = acc[tt][r];
        }
    }
#pragma unroll
    for (int r = 0; r < 4; r++) {
        int orow = rowD0 + r;
        if (orow < N_) {
            if (l15 < 4) s1s[orow * 4 + l15] = acc[16][r];
            else if (l15 < 8) s1d[orow * 4 + (l15 - 4)] = acc[16][r];
        }
    }
}

// ---------------- att1: 2 gather passes; writes UNNORMALIZED exp + sinv1 ----------------

__global__ __launch_bounds__(256) void k_att1(const int* __restrict__ rowptr, const int* __restrict__ csr,
                                              const float* __restrict__ s1s, const float* __restrict__ s1d,
                                              float* __restrict__ att1, float* __restrict__ sinv1) {
    int t = threadIdx.x;
    int wv = t >> 6, l = t & 63;
    int n = blockIdx.x * 4 + wv;
    int base = rowptr[n], deg = rowptr[n + 1] - base;
    int i = l >> 2, hh = l & 3;
    float sdw = s1d[n * 4 + hh];

    float mx = -INFINITY;
    for (int ib = 0; ib < deg; ib += 16) {
        int e = ib + i;
        if (e < deg) {
            int s = csr[base + e];
            float v = s1s[s * 4 + hh] + sdw;
            v = v > 0.f ? v : ALPHA * v;
            mx = fmaxf(mx, v);
        }
    }
    for (int o = 4; o < 64; o <<= 1) mx = fmaxf(mx, __shfl_xor(mx, o));
    float sm = 0.f;
    for (int ib = 0; ib < deg; ib += 16) {
        int e = ib + i;
        if (e < deg) {
            int s = csr[base + e];
            float v = s1s[s * 4 + hh] + sdw;
            v = v > 0.f ? v : ALPHA * v;
            float ex = expf(v - mx);
            att1[(size_t)(base + e) * 4 + hh] = ex;   // unnormalized
            sm += ex;
        }
    }
    for (int o = 4; o < 64; o <<= 1) sm += __shfl_xor(sm, o);
    if (l < 4) sinv1[n * 4 + hh] = (deg > 0) ? 1.f / sm : 0.f;
}

// ---------------- layer-1 aggregate + normalize + ELU + GEMM2 + s2 scores, fused,
// PERSISTENT. 1024 blocks (4/CU: LDS exactly 40960B, no xs), 8 waves/block.
// Gather: proven 4-edge unroll, plain loads. GEMM2 tail: readlane broadcast of
// acc (bit-exact same summation order as the xs-LDS tail; lane j holds x[4j..4j+3]).
// NO forced min-waves (r13 spill lesson); natural VGPR ~56 supports 8 waves/SIMD.

constexpr int AGG_BLOCKS = 1024;
constexpr int NODES_PER_SWEEP = AGG_BLOCKS * 8;

__global__ __launch_bounds__(512) void k_agg1g(const int* __restrict__ rowptr, const int* __restrict__ csr,
                                               const float* __restrict__ att1, const float* __restrict__ sinv1,
                                               const float* __restrict__ Wh1,
                                               const float* __restrict__ Wo, const float* __restrict__ ao,
                                               float* __restrict__ Wh2,
                                               float* __restrict__ s2s, float* __restrict__ s2d) {
    __shared__ float WoS[256 * 40];   // 40960B exactly -> 4 blocks/CU (163840B = full LDS)
    int t = threadIdx.x;
#pragma unroll
    for (int u = 0; u < 5; u++) {
        int idx = (u * 512 + t) * 4;
        *(float4*)(&WoS[idx]) = *(const float4*)(&Wo[idx]);
    }
    __syncthreads();   // once per block

    int w = t >> 6, lane = t & 63;
    int f = lane << 2;
    int hw = lane >> 4;
    int lane40 = (lane < 40) ? lane : 0;   // lanes>=40: broadcast read, result unused
    float a1 = (lane < 40) ? ao[lane] : 0.f;
    float a2 = (lane < 40) ? ao[40 + lane] : 0.f;

    for (int n = blockIdx.x * 8 + w; n < N_; n += NODES_PER_SWEEP) {
        int base = rowptr[n], deg = rowptr[n + 1] - base;

        float4 acc = make_float4(0.f, 0.f, 0.f, 0.f);
        int i = 0;
        for (; i + 3 < deg; i += 4) {
            int b0 = base + i;
            int s0 = csr[b0], s1 = csr[b0 + 1], s2 = csr[b0 + 2], s3 = csr[b0 + 3];
            float at0 = att1[(size_t)b0 * 4 + hw];
            float at1 = att1[(size_t)(b0 + 1) * 4 + hw];
            float at2 = att1[(size_t)(b0 + 2) * 4 + hw];
            float at3 = att1[(size_t)(b0 + 3) * 4 + hw];
            float4 v0 = *(const float4*)(Wh1 + (size_t)s0 * 256 + f);
            float4 v1 = *(const float4*)(Wh1 + (size_t)s1 * 256 + f);
            float4 v2 = *(const float4*)(Wh1 + (size_t)s2 * 256 + f);
            float4 v3 = *(const float4*)(Wh1 + (size_t)s3 * 256 + f);
            acc.x += at0 * v0.x + at1 * v1.x + at2 * v2.x + at3 * v3.x;
            acc.y += at0 * v0.y + at1 * v1.y + at2 * v2.y + at3 * v3.y;
            acc.z += at0 * v0.z + at1 * v1.z + at2 * v2.z + at3 * v3.z;
            acc.w += at0 * v0.w + at1 * v1.w + at2 * v2.w + at3 * v3.w;
        }
        for (; i < deg; i++) {
            int s0 = csr[base + i];
            float at0 = att1[(size_t)(base + i) * 4 + hw];
            float4 v0 = *(const float4*)(Wh1 + (size_t)s0 * 256 + f);
            acc.x += at0 * v0.x;
            acc.y += at0 * v0.y;
            acc.z += at0 * v0.z;
            acc.w += at0 * v0.w;
        }
        // fold softmax normalization (deferred from att1), then ELU
        float inv = sinv1[n * 4 + hw];
        acc.x *= inv; acc.y *= inv; acc.z *= inv; acc.w *= inv;
        acc.x = acc.x > 0.f ? acc.x : (expf(acc.x) - 1.f);
        acc.y = acc.y > 0.f ? acc.y : (expf(acc.y) - 1.f);
        acc.z = acc.z > 0.f ? acc.z : (expf(acc.z) - 1.f);
        acc.w = acc.w > 0.f ? acc.w : (expf(acc.w) - 1.f);

        // GEMM2 tail: x[k=4j+q] lives in lane j component q; broadcast via readlane.
        // Same summation order as the xs-LDS tail (bit-exact).
        float o = 0.f;
        for (int j = 0; j < 64; j++) {
            float x0 = __uint_as_float(__builtin_amdgcn_readlane(__float_as_uint(acc.x), j));
            float x1 = __uint_as_float(__builtin_amdgcn_readlane(__float_as_uint(acc.y), j));
            float x2 = __uint_as_float(__builtin_amdgcn_readlane(__float_as_uint(acc.z), j));
            float x3 = __uint_as_float(__builtin_amdgcn_readlane(__float_as_uint(acc.w), j));
            int k4 = j * 4;
            o += x0 * WoS[k4 * 40 + lane40] + x1 * WoS[(k4 + 1) * 40 + lane40] +
                 x2 * WoS[(k4 + 2) * 40 + lane40] + x3 * WoS[(k4 + 3) * 40 + lane40];
        }
        if (lane < 40) Wh2[(size_t)n * 40 + lane] = o;

        float r1 = o * a1, r2 = o * a2;
        for (int off = 32; off; off >>= 1) {
            r1 += __shfl_xor(r1, off);
            r2 += __shfl_xor(r2, off);
        }
        if (lane == 0) {
            s2s[n] = r1;
            s2d[n] = r2;
        }
    }
}

// ---------------- layer-2: att2 inline; 8-edge x 8-lane class-interleave.
// Lane (e8,c8) owns classes c8+8q (q=0..4): Wh2 row reads coalesce into
// five 32B segments per edge. Per-class sums bit-identical to r14 layout.

__global__ __launch_bounds__(256) void k_l2(const int* __restrict__ rowptr, const int* __restrict__ csr,
                                            const float* __restrict__ s2s, const float* __restrict__ s2d,
                                            const float* __restrict__ Wh2, float* __restrict__ out) {
    int t = threadIdx.x;
    int wv = t >> 6, lane = t & 63;
    int n = blockIdx.x * 4 + wv;
    int base = rowptr[n], deg = rowptr[n + 1] - base;
    float sdw = s2d[n];

    // pass 1: max over edges (64-way)
    float mx = -INFINITY;
    for (int i = lane; i < deg; i += 64) {
        int s = csr[base + i];
        float e = s2s[s] + sdw;
        e = e > 0.f ? e : ALPHA * e;
        mx = fmaxf(mx, e);
    }
    for (int o = 32; o; o >>= 1) mx = fmaxf(mx, __shfl_xor(mx, o));

    // pass 2: 8 edges in flight; lane accumulates classes c8+8q
    int e8 = lane >> 3, c8 = lane & 7;
    float acc0 = 0.f, acc1 = 0.f, acc2 = 0.f, acc3 = 0.f, acc4 = 0.f;
    float smp = 0.f;
    for (int i = e8; i < deg; i += 8) {
        int s = csr[base + i];
        float e = s2s[s] + sdw;
        e = e > 0.f ? e : ALPHA * e;
        float a = expf(e - mx);
        smp += a;
        const float* wp = Wh2 + (size_t)s * 40 + c8;
        acc0 += a * wp[0];
        acc1 += a * wp[8];
        acc2 += a * wp[16];
        acc3 += a * wp[24];
        acc4 += a * wp[32];
    }
    for (int o = 8; o < 64; o <<= 1) {
        smp += __shfl_xor(smp, o);
        acc0 += __shfl_xor(acc0, o);
        acc1 += __shfl_xor(acc1, o);
        acc2 += __shfl_xor(acc2, o);
        acc3 += __shfl_xor(acc3, o);
        acc4 += __shfl_xor(acc4, o);
    }
    float inv = (deg > 0) ? 1.f / smp : 0.f;
    acc0 *= inv; acc1 *= inv; acc2 *= inv; acc3 *= inv; acc4 *= inv;

    // log_softmax over 40 classes (reduce across c8: masks 1,2,4)
    float mv = fmaxf(fmaxf(fmaxf(acc0, acc1), fmaxf(acc2, acc3)), acc4);
    for (int o = 1; o < 8; o <<= 1) mv = fmaxf(mv, __shfl_xor(mv, o));
    float se = expf(acc0 - mv) + expf(acc1 - mv) + expf(acc2 - mv) +
               expf(acc3 - mv) + expf(acc4 - mv);
    for (int o = 1; o < 8; o <<= 1) se += __shfl_xor(se, o);
    float lse = logf(se);
    if (e8 == 0) {
        float* op = out + (size_t)n * 40 + c8;
        op[0]  = acc0 - mv - lse;
        op[8]  = acc1 - mv - lse;
        op[16] = acc2 - mv - lse;
        op[24] = acc3 - mv - lse;
        op[32] = acc4 - mv - lse;
    }
}

// ---------------- host ----------------

extern "C" void kernel_launch(void* const* d_in, const int* in_sizes, int n_in,
                              void* d_out, int out_size, void* d_ws, size_t ws_size,
                              hipStream_t stream) {
    const float* h   = (const float*)d_in[0];
    const int*   ei  = (const int*)d_in[1];
    const float* Whd = (const float*)d_in[2];
    const float* ah  = (const float*)d_in[3];
    const float* Wo  = (const float*)d_in[4];
    const float* ao  = (const float*)d_in[5];
    float* out = (float*)d_out;

    const int* src = ei;
    const int* dst = ei + E_;
    const int nchunks = (N_ + 1023) / 1024;

    char* ws = (char*)d_ws;
    size_t off = 0;
    auto alloc = [&](size_t bytes) -> char* {
        size_t a = (off + 255) & ~(size_t)255;
        off = a + bytes;
        return ws + a;
    };
    int* rowptr = (int*)alloc((size_t)(N_ + 1) * 4);
    int* cursor = (int*)alloc((size_t)N_ * 4);
    int* deg    = (int*)alloc((size_t)N_ * 4);
    int* part   = (int*)alloc((size_t)(nchunks + 1) * 4);
    int* csr    = (int*)alloc((size_t)E_ * 4);
    float* s1s  = (float*)alloc((size_t)N_ * 4 * 4);
    float* s1d  = (float*)alloc((size_t)N_ * 4 * 4);
    float* sinv1= (float*)alloc((size_t)N_ * 4 * 4);
    float* Wh2  = (float*)alloc((size_t)N_ * 40 * 4);
    float* s2s  = (float*)alloc((size_t)N_ * 4);
    float* s2d  = (float*)alloc((size_t)N_ * 4);
    __bf16* Bh  = (__bf16*)alloc((size_t)8 * 272 * 32 * 2);   // 136 KB
    __bf16* Bl  = (__bf16*)alloc((size_t)8 * 272 * 32 * 2);
    float* att1 = (float*)alloc((size_t)E_ * 4 * 4);   // 25.6 MB
    float* Wh1  = (float*)alloc((size_t)N_ * 256 * 4); // 102.4 MB
    size_t need = off + 256;                            // ~157 MB total

    if (ws_size < need) {
        k_sent<<<(int)((OUTEL + 255) / 256), 256, 0, stream>>>(out, OUTEL, -2.0f);
        return;
    }

    // B prep (independent of CSR)
    k_prepB<<<256, 320, 0, stream>>>(Whd, ah, Bh, Bl);

    // CSR build
    k_zero<<<(N_ + 255) / 256, 256, 0, stream>>>(deg, N_);
    k_count<<<(E_ + 255) / 256, 256, 0, stream>>>(dst, deg);
    k_partial<<<nchunks, 256, 0, stream>>>(deg, part);
    k_scan_part<<<1, 64, 0, stream>>>(part, nchunks, rowptr);
    k_scan_final<<<nchunks, 256, 0, stream>>>(deg, part, rowptr, cursor);
    k_fill<<<(E_ + 255) / 256, 256, 0, stream>>>(src, dst, cursor, csr);

    // layer 1: MFMA GEMM (Wh1 + s1 scores), att1 (2 passes, unnormalized + sinv1)
    k_gemm1m<<<(N_ + 63) / 64, 256, 0, stream>>>(h, Bh, Bl, Wh1, s1s, s1d);
    k_att1<<<N_ / 4, 256, 0, stream>>>(rowptr, csr, s1s, s1d, att1, sinv1);

    // fused aggregate + normalize + ELU + gemm2 + s2 scores (persistent, 4 blk/CU)
    k_agg1g<<<AGG_BLOCKS, 512, 0, stream>>>(rowptr, csr, att1, sinv1, Wh1, Wo, ao, Wh2, s2s, s2d);

    // layer 2 (att2 + denominator fused; 8-edge ILP, coalesced Wh2 reads)
    k_l2<<<N_ / 4, 256, 0, stream>>>(rowptr, csr, s2s, s2d, Wh2, out);
}

// Round 7
// 812.898 us; speedup vs baseline: 2.7647x; 1.0621x over previous
//
#include <hip/hip_runtime.h>

// GAT: N=100000 E=1600000 NFEAT=256 NHID=64 NHEADS=4 NCLASS=40 (hardcoded dims).
// r15 (863us): readlane tail regressed agg1g 244->280 (VALU 78%, 25.6M conflicts);
// xs-LDS tail is the proven winner. Non-agg stable ~583us.
// r16: agg1g = r12's exact xs-tail body, but 1024-thread blocks (16 waves):
// LDS 57344B -> 2 blocks/CU = 32 waves/CU (HW max, was 24), WoS staged 2x/CU.
// Grid 512 persistent. k_scan_part: 1-thread serial scan -> 128-thread
// Hillis-Steele (saves ~25us of pure latency). All else unchanged from r15.

#define ALPHA 0.2f
constexpr int N_ = 100000;
constexpr int E_ = 1600000;
constexpr long OUTEL = (long)N_ * 40;

typedef __bf16 bf16x8 __attribute__((ext_vector_type(8)));
typedef float f32x4 __attribute__((ext_vector_type(4)));

__global__ void k_sent(float* out, long n, float v) {
    long i = blockIdx.x * 256L + threadIdx.x;
    if (i < n) out[i] = v;
}

// ---------------- CSR build ----------------

__global__ void k_zero(int* p, int n) {
    int i = blockIdx.x * 256 + threadIdx.x;
    if (i < n) p[i] = 0;
}

__global__ void k_count(const int* __restrict__ dst, int* __restrict__ deg) {
    int e = blockIdx.x * 256 + threadIdx.x;
    if (e < E_) {
        int d = dst[e];
        if ((unsigned)d < (unsigned)N_) atomicAdd(&deg[d], 1);
    }
}

__global__ void k_partial(const int* __restrict__ deg, int* __restrict__ part) {
    __shared__ int sd[256];
    int b = blockIdx.x, t = threadIdx.x;
    int base = b * 1024;
    int s = 0;
    for (int i = 0; i < 4; i++) {
        int idx = base + t * 4 + i;
        if (idx < N_) s += deg[idx];
    }
    sd[t] = s;
    __syncthreads();
    for (int o = 128; o; o >>= 1) {
        if (t < o) sd[t] += sd[t + o];
        __syncthreads();
    }
    if (t == 0) part[b] = sd[0];
}

// parallel exclusive scan over nchunks (<=128) partials; total -> rowptr[N_]
__global__ void k_scan_part(int* part, int nchunks, int* rowptr) {
    __shared__ int sd[128];
    int t = threadIdx.x;
    int v = (t < nchunks) ? part[t] : 0;
    sd[t] = v;
    __syncthreads();
    for (int o = 1; o < 128; o <<= 1) {
        int add = (t >= o) ? sd[t - o] : 0;
        __syncthreads();
        sd[t] += add;
        __syncthreads();
    }
    if (t < nchunks) part[t] = sd[t] - v;   // exclusive
    if (t == 127) rowptr[N_] = sd[127];     // total (padding adds zeros)
}

__global__ void k_scan_final(const int* __restrict__ deg, const int* __restrict__ part,
                             int* __restrict__ rowptr, int* __restrict__ cursor) {
    __shared__ int sd[256];
    int b = blockIdx.x, t = threadIdx.x;
    int base = b * 1024;
    int v[4];
    int s = 0;
    for (int i = 0; i < 4; i++) {
        int idx = base + t * 4 + i;
        v[i] = (idx < N_) ? deg[idx] : 0;
        s += v[i];
    }
    sd[t] = s;
    __syncthreads();
    for (int o = 1; o < 256; o <<= 1) {
        int add = (t >= o) ? sd[t - o] : 0;
        __syncthreads();
        sd[t] += add;
        __syncthreads();
    }
    int off0 = part[b] + (sd[t] - s);
    for (int i = 0; i < 4; i++) {
        int idx = base + t * 4 + i;
        if (idx < N_) {
            rowptr[idx] = off0;
            cursor[idx] = off0;
            off0 += v[i];
        }
    }
}

__global__ void k_fill(const int* __restrict__ src, const int* __restrict__ dst,
                       int* __restrict__ cursor, int* __restrict__ csr) {
    int e = blockIdx.x * 256 + threadIdx.x;
    if (e < E_) {
        int d = dst[e];
        if ((unsigned)d < (unsigned)N_) {
            int p = atomicAdd(&cursor[d], 1);
            if ((unsigned)p < (unsigned)E_) csr[p] = src[e];
        }
    }
}

// ---------------- B prep: transpose + bf16 hi/lo split + wa columns ----------------

__global__ __launch_bounds__(320) void k_prepB(const float* __restrict__ Whd,
                                               const float* __restrict__ ah,
                                               __bf16* __restrict__ Bh, __bf16* __restrict__ Bl) {
    int k = blockIdx.x;      // 0..255
    int c = threadIdx.x;     // 0..319
    if (c >= 272) return;
    float v = 0.f;
    if (c < 256) {
        v = Whd[(c >> 6) * 16384 + k * 64 + (c & 63)];
    } else if (c < 264) {
        int hh = (c - 256) & 3;
        int isd = (c >= 260) ? 64 : 0;
        const float* wp = Whd + hh * 16384 + k * 64;
        const float* ap = ah + hh * 128 + isd;
        float s = 0.f;
        for (int j = 0; j < 64; j++) s += wp[j] * ap[j];
        v = s;
    }
    __bf16 hi = (__bf16)v;
    __bf16 lo = (__bf16)(v - (float)hi);
    size_t idx = ((size_t)(k >> 5) * 272 + c) * 32 + (k & 31);
    Bh[idx] = hi;
    Bl[idx] = lo;
}

// ---------------- GEMM1 via MFMA 16x16x32 bf16, split-precision (3 terms) ----------------

__global__ __launch_bounds__(256) void k_gemm1m(const float* __restrict__ h,
                                                const __bf16* __restrict__ Bh,
                                                const __bf16* __restrict__ Bl,
                                                float* __restrict__ Wh1,
                                                float* __restrict__ s1s,
                                                float* __restrict__ s1d) {
    int t = threadIdx.x;
    int wv = t >> 6, l = t & 63;
    int l15 = l & 15, lg = l >> 4;
    int rowA = blockIdx.x * 64 + wv * 16 + l15;
    bool rok = rowA < N_;
    const float* hp = h + (size_t)rowA * 256 + lg * 8;

    f32x4 acc[17];
#pragma unroll
    for (int i = 0; i < 17; i++) acc[i] = (f32x4){0.f, 0.f, 0.f, 0.f};

    for (int kc = 0; kc < 8; kc++) {
        float va[8] = {0.f, 0.f, 0.f, 0.f, 0.f, 0.f, 0.f, 0.f};
        if (rok) {
            float4 p = *(const float4*)(hp + kc * 32);
            float4 q = *(const float4*)(hp + kc * 32 + 4);
            va[0] = p.x; va[1] = p.y; va[2] = p.z; va[3] = p.w;
            va[4] = q.x; va[5] = q.y; va[6] = q.z; va[7] = q.w;
        }
        bf16x8 ahi, alo;
#pragma unroll
        for (int j = 0; j < 8; j++) {
            __bf16 hi = (__bf16)va[j];
            ahi[j] = hi;
            alo[j] = (__bf16)(va[j] - (float)hi);
        }
        const __bf16* bph = Bh + ((size_t)kc * 272 + l15) * 32 + lg * 8;
        const __bf16* bpl = Bl + ((size_t)kc * 272 + l15) * 32 + lg * 8;
#pragma unroll
        for (int tt = 0; tt < 17; tt++) {
            bf16x8 bh = *(const bf16x8*)(bph + tt * 512);
            bf16x8 bl = *(const bf16x8*)(bpl + tt * 512);
            acc[tt] = __builtin_amdgcn_mfma_f32_16x16x32_bf16(ahi, bh, acc[tt], 0, 0, 0);
            acc[tt] = __builtin_amdgcn_mfma_f32_16x16x32_bf16(alo, bh, acc[tt], 0, 0, 0);
            acc[tt] = __builtin_amdgcn_mfma_f32_16x16x32_bf16(ahi, bl, acc[tt], 0, 0, 0);
        }
    }

    int rowD0 = blockIdx.x * 64 + wv * 16 + lg * 4;
#pragma unroll
    for (int tt = 0; tt < 16; tt++) {
#pragma unroll
        for (int r = 0; r < 4; r++) {
            int orow = rowD0 + r;
            if (orow < N_) Wh1[(size_t)orow * 256 + tt * 16 + l15] = acc[tt][r];
        }
    }
#pragma unroll
    for (int r = 0; r < 4; r++) {
        int orow = rowD0 + r;
        if (orow < N_) {
            if (l15 < 4) s1s[orow * 4 + l15] = acc[16][r];
            else if (l15 < 8) s1d[orow * 4 + (l15 - 4)] = acc[16][r];
        }
    }
}

// ---------------- att1: 2 gather passes; writes UNNORMALIZED exp + sinv1 ----------------

__global__ __launch_bounds__(256) void k_att1(const int* __restrict__ rowptr, const int* __restrict__ csr,
                                              const float* __restrict__ s1s, const float* __restrict__ s1d,
                                              float* __restrict__ att1, float* __restrict__ sinv1) {
    int t = threadIdx.x;
    int wv = t >> 6, l = t & 63;
    int n = blockIdx.x * 4 + wv;
    int base = rowptr[n], deg = rowptr[n + 1] - base;
    int i = l >> 2, hh = l & 3;
    float sdw = s1d[n * 4 + hh];

    float mx = -INFINITY;
    for (int ib = 0; ib < deg; ib += 16) {
        int e = ib + i;
        if (e < deg) {
            int s = csr[base + e];
            float v = s1s[s * 4 + hh] + sdw;
            v = v > 0.f ? v : ALPHA * v;
            mx = fmaxf(mx, v);
        }
    }
    for (int o = 4; o < 64; o <<= 1) mx = fmaxf(mx, __shfl_xor(mx, o));
    float sm = 0.f;
    for (int ib = 0; ib < deg; ib += 16) {
        int e = ib + i;
        if (e < deg) {
            int s = csr[base + e];
            float v = s1s[s * 4 + hh] + sdw;
            v = v > 0.f ? v : ALPHA * v;
            float ex = expf(v - mx);
            att1[(size_t)(base + e) * 4 + hh] = ex;   // unnormalized
            sm += ex;
        }
    }
    for (int o = 4; o < 64; o <<= 1) sm += __shfl_xor(sm, o);
    if (l < 4) sinv1[n * 4 + hh] = (deg > 0) ? 1.f / sm : 0.f;
}

// ---------------- layer-1 aggregate + normalize + ELU + GEMM2 + s2 scores, fused,
// PERSISTENT. 512 blocks x 1024 threads (16 waves): LDS 57344B -> 2 blocks/CU
// = 32 waves/CU (HW max). Body identical to r12's proven xs-tail (bit-exact).
// 4-edge unroll gather, plain loads, natural VGPR (no forced min-waves).

constexpr int AGG_BLOCKS = 512;
constexpr int AGG_WAVES = 16;
constexpr int NODES_PER_SWEEP = AGG_BLOCKS * AGG_WAVES;

__global__ __launch_bounds__(1024) void k_agg1g(const int* __restrict__ rowptr, const int* __restrict__ csr,
                                                const float* __restrict__ att1, const float* __restrict__ sinv1,
                                                const float* __restrict__ Wh1,
                                                const float* __restrict__ Wo, const float* __restrict__ ao,
                                                float* __restrict__ Wh2,
                                                float* __restrict__ s2s, float* __restrict__ s2d) {
    __shared__ float WoS[256 * 40];        // 40960B
    __shared__ float xs[AGG_WAVES][256];   // 16384B  -> total 57344B, 2 blocks/CU
    int t = threadIdx.x;
#pragma unroll
    for (int u = 0; u < 10; u++) {
        int idx = (u * 1024 + t) * 4;
        if (idx < 256 * 40) *(float4*)(&WoS[idx]) = *(const float4*)(&Wo[idx]);
    }
    __syncthreads();   // once per block

    int w = t >> 6, lane = t & 63;
    int f = lane << 2;
    int hw = lane >> 4;
    float a1 = (lane < 40) ? ao[lane] : 0.f;
    float a2 = (lane < 40) ? ao[40 + lane] : 0.f;

    for (int n = blockIdx.x * AGG_WAVES + w; n < N_; n += NODES_PER_SWEEP) {
        int base = rowptr[n], deg = rowptr[n + 1] - base;

        float4 acc = make_float4(0.f, 0.f, 0.f, 0.f);
        int i = 0;
        for (; i + 3 < deg; i += 4) {
            int b0 = base + i;
            int s0 = csr[b0], s1 = csr[b0 + 1], s2 = csr[b0 + 2], s3 = csr[b0 + 3];
            float at0 = att1[(size_t)b0 * 4 + hw];
            float at1 = att1[(size_t)(b0 + 1) * 4 + hw];
            float at2 = att1[(size_t)(b0 + 2) * 4 + hw];
            float at3 = att1[(size_t)(b0 + 3) * 4 + hw];
            float4 v0 = *(const float4*)(Wh1 + (size_t)s0 * 256 + f);
            float4 v1 = *(const float4*)(Wh1 + (size_t)s1 * 256 + f);
            float4 v2 = *(const float4*)(Wh1 + (size_t)s2 * 256 + f);
            float4 v3 = *(const float4*)(Wh1 + (size_t)s3 * 256 + f);
            acc.x += at0 * v0.x + at1 * v1.x + at2 * v2.x + at3 * v3.x;
            acc.y += at0 * v0.y + at1 * v1.y + at2 * v2.y + at3 * v3.y;
            acc.z += at0 * v0.z + at1 * v1.z + at2 * v2.z + at3 * v3.z;
            acc.w += at0 * v0.w + at1 * v1.w + at2 * v2.w + at3 * v3.w;
        }
        for (; i < deg; i++) {
            int s0 = csr[base + i];
            float at0 = att1[(size_t)(base + i) * 4 + hw];
            float4 v0 = *(const float4*)(Wh1 + (size_t)s0 * 256 + f);
            acc.x += at0 * v0.x;
            acc.y += at0 * v0.y;
            acc.z += at0 * v0.z;
            acc.w += at0 * v0.w;
        }
        // fold softmax normalization (deferred from att1), then ELU
        float inv = sinv1[n * 4 + hw];
        acc.x *= inv; acc.y *= inv; acc.z *= inv; acc.w *= inv;
        acc.x = acc.x > 0.f ? acc.x : (expf(acc.x) - 1.f);
        acc.y = acc.y > 0.f ? acc.y : (expf(acc.y) - 1.f);
        acc.z = acc.z > 0.f ? acc.z : (expf(acc.z) - 1.f);
        acc.w = acc.w > 0.f ? acc.w : (expf(acc.w) - 1.f);
        *(float4*)(&xs[w][f]) = acc;
        // wave-private LDS RAW: compiler inserts lgkmcnt wait; no barrier needed.

        // GEMM2 tail: lanes 0..39 compute Wh2[n][c]; xs reads are wave-uniform broadcast.
        float o = 0.f;
        if (lane < 40) {
            for (int k = 0; k < 256; k += 4) {
                float4 xk = *(const float4*)(&xs[w][k]);
                o += xk.x * WoS[k * 40 + lane] + xk.y * WoS[(k + 1) * 40 + lane] +
                     xk.z * WoS[(k + 2) * 40 + lane] + xk.w * WoS[(k + 3) * 40 + lane];
            }
            Wh2[(size_t)n * 40 + lane] = o;
        }
        float r1 = o * a1, r2 = o * a2;
        for (int off = 32; off; off >>= 1) {
            r1 += __shfl_xor(r1, off);
            r2 += __shfl_xor(r2, off);
        }
        if (lane == 0) {
            s2s[n] = r1;
            s2d[n] = r2;
        }
    }
}

// ---------------- layer-2: att2 inline; 8-edge x 8-lane class-interleave ----------------

__global__ __launch_bounds__(256) void k_l2(const int* __restrict__ rowptr, const int* __restrict__ csr,
                                            const float* __restrict__ s2s, const float* __restrict__ s2d,
                                            const float* __restrict__ Wh2, float* __restrict__ out) {
    int t = threadIdx.x;
    int wv = t >> 6, lane = t & 63;
    int n = blockIdx.x * 4 + wv;
    int base = rowptr[n], deg = rowptr[n + 1] - base;
    float sdw = s2d[n];

    // pass 1: max over edges (64-way)
    float mx = -INFINITY;
    for (int i = lane; i < deg; i += 64) {
        int s = csr[base + i];
        float e = s2s[s] + sdw;
        e = e > 0.f ? e : ALPHA * e;
        mx = fmaxf(mx, e);
    }
    for (int o = 32; o; o >>= 1) mx = fmaxf(mx, __shfl_xor(mx, o));

    // pass 2: 8 edges in flight; lane accumulates classes c8+8q
    int e8 = lane >> 3, c8 = lane & 7;
    float acc0 = 0.f, acc1 = 0.f, acc2 = 0.f, acc3 = 0.f, acc4 = 0.f;
    float smp = 0.f;
    for (int i = e8; i < deg; i += 8) {
        int s = csr[base + i];
        float e = s2s[s] + sdw;
        e = e > 0.f ? e : ALPHA * e;
        float a = expf(e - mx);
        smp += a;
        const float* wp = Wh2 + (size_t)s * 40 + c8;
        acc0 += a * wp[0];
        acc1 += a * wp[8];
        acc2 += a * wp[16];
        acc3 += a * wp[24];
        acc4 += a * wp[32];
    }
    for (int o = 8; o < 64; o <<= 1) {
        smp += __shfl_xor(smp, o);
        acc0 += __shfl_xor(acc0, o);
        acc1 += __shfl_xor(acc1, o);
        acc2 += __shfl_xor(acc2, o);
        acc3 += __shfl_xor(acc3, o);
        acc4 += __shfl_xor(acc4, o);
    }
    float inv = (deg > 0) ? 1.f / smp : 0.f;
    acc0 *= inv; acc1 *= inv; acc2 *= inv; acc3 *= inv; acc4 *= inv;

    // log_softmax over 40 classes (reduce across c8: masks 1,2,4)
    float mv = fmaxf(fmaxf(fmaxf(acc0, acc1), fmaxf(acc2, acc3)), acc4);
    for (int o = 1; o < 8; o <<= 1) mv = fmaxf(mv, __shfl_xor(mv, o));
    float se = expf(acc0 - mv) + expf(acc1 - mv) + expf(acc2 - mv) +
               expf(acc3 - mv) + expf(acc4 - mv);
    for (int o = 1; o < 8; o <<= 1) se += __shfl_xor(se, o);
    float lse = logf(se);
    if (e8 == 0) {
        float* op = out + (size_t)n * 40 + c8;
        op[0]  = acc0 - mv - lse;
        op[8]  = acc1 - mv - lse;
        op[16] = acc2 - mv - lse;
        op[24] = acc3 - mv - lse;
        op[32] = acc4 - mv - lse;
    }
}

// ---------------- host ----------------

extern "C" void kernel_launch(void* const* d_in, const int* in_sizes, int n_in,
                              void* d_out, int out_size, void* d_ws, size_t ws_size,
                              hipStream_t stream) {
    const float* h   = (const float*)d_in[0];
    const int*   ei  = (const int*)d_in[1];
    const float* Whd = (const float*)d_in[2];
    const float* ah  = (const float*)d_in[3];
    const float* Wo  = (const float*)d_in[4];
    const float* ao  = (const float*)d_in[5];
    float* out = (float*)d_out;

    const int* src = ei;
    const int* dst = ei + E_;
    const int nchunks = (N_ + 1023) / 1024;

    char* ws = (char*)d_ws;
    size_t off = 0;
    auto alloc = [&](size_t bytes) -> char* {
        size_t a = (off + 255) & ~(size_t)255;
        off = a + bytes;
        return ws + a;
    };
    int* rowptr = (int*)alloc((size_t)(N_ + 1) * 4);
    int* cursor = (int*)alloc((size_t)N_ * 4);
    int* deg    = (int*)alloc((size_t)N_ * 4);
    int* part   = (int*)alloc((size_t)(nchunks + 1) * 4);
    int* csr    = (int*)alloc((size_t)E_ * 4);
    float* s1s  = (float*)alloc((size_t)N_ * 4 * 4);
    float* s1d  = (float*)alloc((size_t)N_ * 4 * 4);
    float* sinv1= (float*)alloc((size_t)N_ * 4 * 4);
    float* Wh2  = (float*)alloc((size_t)N_ * 40 * 4);
    float* s2s  = (float*)alloc((size_t)N_ * 4);
    float* s2d  = (float*)alloc((size_t)N_ * 4);
    __bf16* Bh  = (__bf16*)alloc((size_t)8 * 272 * 32 * 2);   // 136 KB
    __bf16* Bl  = (__bf16*)alloc((size_t)8 * 272 * 32 * 2);
    float* att1 = (float*)alloc((size_t)E_ * 4 * 4);   // 25.6 MB
    float* Wh1  = (float*)alloc((size_t)N_ * 256 * 4); // 102.4 MB
    size_t need = off + 256;                            // ~157 MB total

    if (ws_size < need) {
        k_sent<<<(int)((OUTEL + 255) / 256), 256, 0, stream>>>(out, OUTEL, -2.0f);
        return;
    }

    // B prep (independent of CSR)
    k_prepB<<<256, 320, 0, stream>>>(Whd, ah, Bh, Bl);

    // CSR build
    k_zero<<<(N_ + 255) / 256, 256, 0, stream>>>(deg, N_);
    k_count<<<(E_ + 255) / 256, 256, 0, stream>>>(dst, deg);
    k_partial<<<nchunks, 256, 0, stream>>>(deg, part);
    k_scan_part<<<1, 128, 0, stream>>>(part, nchunks, rowptr);
    k_scan_final<<<nchunks, 256, 0, stream>>>(deg, part, rowptr, cursor);
    k_fill<<<(E_ + 255) / 256, 256, 0, stream>>>(src, dst, cursor, csr);

    // layer 1: MFMA GEMM (Wh1 + s1 scores), att1 (2 passes, unnormalized + sinv1)
    k_gemm1m<<<(N_ + 63) / 64, 256, 0, stream>>>(h, Bh, Bl, Wh1, s1s, s1d);
    k_att1<<<N_ / 4, 256, 0, stream>>>(rowptr, csr, s1s, s1d, att1, sinv1);

    // fused aggregate + normalize + ELU + gemm2 + s2 scores (persistent, 32 waves/CU)
    k_agg1g<<<AGG_BLOCKS, 1024, 0, stream>>>(rowptr, csr, att1, sinv1, Wh1, Wo, ao, Wh2, s2s, s2d);

    // layer 2 (att2 + denominator fused; 8-edge ILP, coalesced Wh2 reads)
    k_l2<<<N_ / 4, 256, 0, stream>>>(rowptr, csr, s2s, s2d, Wh2, out);
}

// Round 8
// 769.917 us; speedup vs baseline: 2.9191x; 1.0558x over previous
//
#include <hip/hip_runtime.h>

// GAT: N=100000 E=1600000 NFEAT=256 NHID=64 NHEADS=4 NCLASS=40 (hardcoded dims).
// r16 (813us): agg1g FLAT across 3 occupancy configs (24w/32w-4blk/32w-2blk all
// 244-250us) -> NOT concurrency-limited; pinned at ~3.3TB/s beyond-L2 fabric
// on 792MB FETCH. Lever is BYTES, not shape.
// r17: Wh1 stored fp16 (sole consumer = agg1g gather; fp16 rel err 2^-11,
// |Wh1|<~15 safe). Gather row 1024B->512B, logical traffic 1.67->0.85GB.
// gemm1m epilogue converts via v_cvt. Everything else unchanged from r16.

#define ALPHA 0.2f
constexpr int N_ = 100000;
constexpr int E_ = 1600000;
constexpr long OUTEL = (long)N_ * 40;

typedef __bf16 bf16x8 __attribute__((ext_vector_type(8)));
typedef float f32x4 __attribute__((ext_vector_type(4)));

__device__ __forceinline__ unsigned short f2h(float f) {
    _Float16 h = (_Float16)f;
    return *(unsigned short*)&h;
}
__device__ __forceinline__ float h2f(unsigned short u) {
    _Float16 h = *(_Float16*)&u;
    return (float)h;
}

__global__ void k_sent(float* out, long n, float v) {
    long i = blockIdx.x * 256L + threadIdx.x;
    if (i < n) out[i] = v;
}

// ---------------- CSR build ----------------

__global__ void k_zero(int* p, int n) {
    int i = blockIdx.x * 256 + threadIdx.x;
    if (i < n) p[i] = 0;
}

__global__ void k_count(const int* __restrict__ dst, int* __restrict__ deg) {
    int e = blockIdx.x * 256 + threadIdx.x;
    if (e < E_) {
        int d = dst[e];
        if ((unsigned)d < (unsigned)N_) atomicAdd(&deg[d], 1);
    }
}

__global__ void k_partial(const int* __restrict__ deg, int* __restrict__ part) {
    __shared__ int sd[256];
    int b = blockIdx.x, t = threadIdx.x;
    int base = b * 1024;
    int s = 0;
    for (int i = 0; i < 4; i++) {
        int idx = base + t * 4 + i;
        if (idx < N_) s += deg[idx];
    }
    sd[t] = s;
    __syncthreads();
    for (int o = 128; o; o >>= 1) {
        if (t < o) sd[t] += sd[t + o];
        __syncthreads();
    }
    if (t == 0) part[b] = sd[0];
}

// parallel exclusive scan over nchunks (<=128) partials; total -> rowptr[N_]
__global__ void k_scan_part(int* part, int nchunks, int* rowptr) {
    __shared__ int sd[128];
    int t = threadIdx.x;
    int v = (t < nchunks) ? part[t] : 0;
    sd[t] = v;
    __syncthreads();
    for (int o = 1; o < 128; o <<= 1) {
        int add = (t >= o) ? sd[t - o] : 0;
        __syncthreads();
        sd[t] += add;
        __syncthreads();
    }
    if (t < nchunks) part[t] = sd[t] - v;   // exclusive
    if (t == 127) rowptr[N_] = sd[127];     // total
}

__global__ void k_scan_final(const int* __restrict__ deg, const int* __restrict__ part,
                             int* __restrict__ rowptr, int* __restrict__ cursor) {
    __shared__ int sd[256];
    int b = blockIdx.x, t = threadIdx.x;
    int base = b * 1024;
    int v[4];
    int s = 0;
    for (int i = 0; i < 4; i++) {
        int idx = base + t * 4 + i;
        v[i] = (idx < N_) ? deg[idx] : 0;
        s += v[i];
    }
    sd[t] = s;
    __syncthreads();
    for (int o = 1; o < 256; o <<= 1) {
        int add = (t >= o) ? sd[t - o] : 0;
        __syncthreads();
        sd[t] += add;
        __syncthreads();
    }
    int off0 = part[b] + (sd[t] - s);
    for (int i = 0; i < 4; i++) {
        int idx = base + t * 4 + i;
        if (idx < N_) {
            rowptr[idx] = off0;
            cursor[idx] = off0;
            off0 += v[i];
        }
    }
}

__global__ void k_fill(const int* __restrict__ src, const int* __restrict__ dst,
                       int* __restrict__ cursor, int* __restrict__ csr) {
    int e = blockIdx.x * 256 + threadIdx.x;
    if (e < E_) {
        int d = dst[e];
        if ((unsigned)d < (unsigned)N_) {
            int p = atomicAdd(&cursor[d], 1);
            if ((unsigned)p < (unsigned)E_) csr[p] = src[e];
        }
    }
}

// ---------------- B prep: transpose + bf16 hi/lo split + wa columns ----------------

__global__ __launch_bounds__(320) void k_prepB(const float* __restrict__ Whd,
                                               const float* __restrict__ ah,
                                               __bf16* __restrict__ Bh, __bf16* __restrict__ Bl) {
    int k = blockIdx.x;      // 0..255
    int c = threadIdx.x;     // 0..319
    if (c >= 272) return;
    float v = 0.f;
    if (c < 256) {
        v = Whd[(c >> 6) * 16384 + k * 64 + (c & 63)];
    } else if (c < 264) {
        int hh = (c - 256) & 3;
        int isd = (c >= 260) ? 64 : 0;
        const float* wp = Whd + hh * 16384 + k * 64;
        const float* ap = ah + hh * 128 + isd;
        float s = 0.f;
        for (int j = 0; j < 64; j++) s += wp[j] * ap[j];
        v = s;
    }
    __bf16 hi = (__bf16)v;
    __bf16 lo = (__bf16)(v - (float)hi);
    size_t idx = ((size_t)(k >> 5) * 272 + c) * 32 + (k & 31);
    Bh[idx] = hi;
    Bl[idx] = lo;
}

// ---------------- GEMM1 via MFMA 16x16x32 bf16, split-precision (3 terms).
// Wh1 output stored fp16 (sole consumer is the agg1g gather). s1 scores f32.

__global__ __launch_bounds__(256) void k_gemm1m(const float* __restrict__ h,
                                                const __bf16* __restrict__ Bh,
                                                const __bf16* __restrict__ Bl,
                                                unsigned short* __restrict__ Wh1h,
                                                float* __restrict__ s1s,
                                                float* __restrict__ s1d) {
    int t = threadIdx.x;
    int wv = t >> 6, l = t & 63;
    int l15 = l & 15, lg = l >> 4;
    int rowA = blockIdx.x * 64 + wv * 16 + l15;
    bool rok = rowA < N_;
    const float* hp = h + (size_t)rowA * 256 + lg * 8;

    f32x4 acc[17];
#pragma unroll
    for (int i = 0; i < 17; i++) acc[i] = (f32x4){0.f, 0.f, 0.f, 0.f};

    for (int kc = 0; kc < 8; kc++) {
        float va[8] = {0.f, 0.f, 0.f, 0.f, 0.f, 0.f, 0.f, 0.f};
        if (rok) {
            float4 p = *(const float4*)(hp + kc * 32);
            float4 q = *(const float4*)(hp + kc * 32 + 4);
            va[0] = p.x; va[1] = p.y; va[2] = p.z; va[3] = p.w;
            va[4] = q.x; va[5] = q.y; va[6] = q.z; va[7] = q.w;
        }
        bf16x8 ahi, alo;
#pragma unroll
        for (int j = 0; j < 8; j++) {
            __bf16 hi = (__bf16)va[j];
            ahi[j] = hi;
            alo[j] = (__bf16)(va[j] - (float)hi);
        }
        const __bf16* bph = Bh + ((size_t)kc * 272 + l15) * 32 + lg * 8;
        const __bf16* bpl = Bl + ((size_t)kc * 272 + l15) * 32 + lg * 8;
#pragma unroll
        for (int tt = 0; tt < 17; tt++) {
            bf16x8 bh = *(const bf16x8*)(bph + tt * 512);
            bf16x8 bl = *(const bf16x8*)(bpl + tt * 512);
            acc[tt] = __builtin_amdgcn_mfma_f32_16x16x32_bf16(ahi, bh, acc[tt], 0, 0, 0);
            acc[tt] = __builtin_amdgcn_mfma_f32_16x16x32_bf16(alo, bh, acc[tt], 0, 0, 0);
            acc[tt] = __builtin_amdgcn_mfma_f32_16x16x32_bf16(ahi, bl, acc[tt], 0, 0, 0);
        }
    }

    int rowD0 = blockIdx.x * 64 + wv * 16 + lg * 4;
#pragma unroll
    for (int tt = 0; tt < 16; tt++) {
#pragma unroll
        for (int r = 0; r < 4; r++) {
            int orow = rowD0 + r;
            if (orow < N_) Wh1h[(size_t)orow * 256 + tt * 16 + l15] = f2h(acc[tt][r]);
        }
    }
#pragma unroll
    for (int r = 0; r < 4; r++) {
        int orow = rowD0 + r;
        if (orow < N_) {
            if (l15 < 4) s1s[orow * 4 + l15] = acc[16][r];
            else if (l15 < 8) s1d[orow * 4 + (l15 - 4)] = acc[16][r];
        }
    }
}

// ---------------- att1: 2 gather passes; writes UNNORMALIZED exp + sinv1 ----------------

__global__ __launch_bounds__(256) void k_att1(const int* __restrict__ rowptr, const int* __restrict__ csr,
                                              const float* __restrict__ s1s, const float* __restrict__ s1d,
                                              float* __restrict__ att1, float* __restrict__ sinv1) {
    int t = threadIdx.x;
    int wv = t >> 6, l = t & 63;
    int n = blockIdx.x * 4 + wv;
    int base = rowptr[n], deg = rowptr[n + 1] - base;
    int i = l >> 2, hh = l & 3;
    float sdw = s1d[n * 4 + hh];

    float mx = -INFINITY;
    for (int ib = 0; ib < deg; ib += 16) {
        int e = ib + i;
        if (e < deg) {
            int s = csr[base + e];
            float v = s1s[s * 4 + hh] + sdw;
            v = v > 0.f ? v : ALPHA * v;
            mx = fmaxf(mx, v);
        }
    }
    for (int o = 4; o < 64; o <<= 1) mx = fmaxf(mx, __shfl_xor(mx, o));
    float sm = 0.f;
    for (int ib = 0; ib < deg; ib += 16) {
        int e = ib + i;
        if (e < deg) {
            int s = csr[base + e];
            float v = s1s[s * 4 + hh] + sdw;
            v = v > 0.f ? v : ALPHA * v;
            float ex = expf(v - mx);
            att1[(size_t)(base + e) * 4 + hh] = ex;   // unnormalized
            sm += ex;
        }
    }
    for (int o = 4; o < 64; o <<= 1) sm += __shfl_xor(sm, o);
    if (l < 4) sinv1[n * 4 + hh] = (deg > 0) ? 1.f / sm : 0.f;
}

// ---------------- layer-1 aggregate + normalize + ELU + GEMM2 + s2 scores, fused,
// PERSISTENT. 512 blocks x 1024 threads (16 waves), LDS 57344B. fp16 Wh1 gather:
// 8B/lane/edge (was 16B). 4-edge unroll, xs-LDS tail (proven), natural VGPR.

constexpr int AGG_BLOCKS = 512;
constexpr int AGG_WAVES = 16;
constexpr int NODES_PER_SWEEP = AGG_BLOCKS * AGG_WAVES;

__global__ __launch_bounds__(1024) void k_agg1g(const int* __restrict__ rowptr, const int* __restrict__ csr,
                                                const float* __restrict__ att1, const float* __restrict__ sinv1,
                                                const unsigned short* __restrict__ Wh1h,
                                                const float* __restrict__ Wo, const float* __restrict__ ao,
                                                float* __restrict__ Wh2,
                                                float* __restrict__ s2s, float* __restrict__ s2d) {
    __shared__ float WoS[256 * 40];        // 40960B
    __shared__ float xs[AGG_WAVES][256];   // 16384B  -> total 57344B
    int t = threadIdx.x;
#pragma unroll
    for (int u = 0; u < 10; u++) {
        int idx = (u * 1024 + t) * 4;
        if (idx < 256 * 40) *(float4*)(&WoS[idx]) = *(const float4*)(&Wo[idx]);
    }
    __syncthreads();   // once per block

    int w = t >> 6, lane = t & 63;
    int f = lane << 2;
    int hw = lane >> 4;
    float a1 = (lane < 40) ? ao[lane] : 0.f;
    float a2 = (lane < 40) ? ao[40 + lane] : 0.f;

    for (int n = blockIdx.x * AGG_WAVES + w; n < N_; n += NODES_PER_SWEEP) {
        int base = rowptr[n], deg = rowptr[n + 1] - base;

        float4 acc = make_float4(0.f, 0.f, 0.f, 0.f);
        int i = 0;
        for (; i + 3 < deg; i += 4) {
            int b0 = base + i;
            int s0 = csr[b0], s1 = csr[b0 + 1], s2 = csr[b0 + 2], s3 = csr[b0 + 3];
            float at0 = att1[(size_t)b0 * 4 + hw];
            float at1 = att1[(size_t)(b0 + 1) * 4 + hw];
            float at2 = att1[(size_t)(b0 + 2) * 4 + hw];
            float at3 = att1[(size_t)(b0 + 3) * 4 + hw];
            ushort4 u0 = *(const ushort4*)(Wh1h + (size_t)s0 * 256 + f);
            ushort4 u1 = *(const ushort4*)(Wh1h + (size_t)s1 * 256 + f);
            ushort4 u2 = *(const ushort4*)(Wh1h + (size_t)s2 * 256 + f);
            ushort4 u3 = *(const ushort4*)(Wh1h + (size_t)s3 * 256 + f);
            acc.x += at0 * h2f(u0.x) + at1 * h2f(u1.x) + at2 * h2f(u2.x) + at3 * h2f(u3.x);
            acc.y += at0 * h2f(u0.y) + at1 * h2f(u1.y) + at2 * h2f(u2.y) + at3 * h2f(u3.y);
            acc.z += at0 * h2f(u0.z) + at1 * h2f(u1.z) + at2 * h2f(u2.z) + at3 * h2f(u3.z);
            acc.w += at0 * h2f(u0.w) + at1 * h2f(u1.w) + at2 * h2f(u2.w) + at3 * h2f(u3.w);
        }
        for (; i < deg; i++) {
            int s0 = csr[base + i];
            float at0 = att1[(size_t)(base + i) * 4 + hw];
            ushort4 u0 = *(const ushort4*)(Wh1h + (size_t)s0 * 256 + f);
            acc.x += at0 * h2f(u0.x);
            acc.y += at0 * h2f(u0.y);
            acc.z += at0 * h2f(u0.z);
            acc.w += at0 * h2f(u0.w);
        }
        // fold softmax normalization (deferred from att1), then ELU
        float inv = sinv1[n * 4 + hw];
        acc.x *= inv; acc.y *= inv; acc.z *= inv; acc.w *= inv;
        acc.x = acc.x > 0.f ? acc.x : (expf(acc.x) - 1.f);
        acc.y = acc.y > 0.f ? acc.y : (expf(acc.y) - 1.f);
        acc.z = acc.z > 0.f ? acc.z : (expf(acc.z) - 1.f);
        acc.w = acc.w > 0.f ? acc.w : (expf(acc.w) - 1.f);
        *(float4*)(&xs[w][f]) = acc;
        // wave-private LDS RAW: compiler inserts lgkmcnt wait; no barrier needed.

        // GEMM2 tail: lanes 0..39 compute Wh2[n][c]; xs reads are wave-uniform broadcast.
        float o = 0.f;
        if (lane < 40) {
            for (int k = 0; k < 256; k += 4) {
                float4 xk = *(const float4*)(&xs[w][k]);
                o += xk.x * WoS[k * 40 + lane] + xk.y * WoS[(k + 1) * 40 + lane] +
                     xk.z * WoS[(k + 2) * 40 + lane] + xk.w * WoS[(k + 3) * 40 + lane];
            }
            Wh2[(size_t)n * 40 + lane] = o;
        }
        float r1 = o * a1, r2 = o * a2;
        for (int off = 32; off; off >>= 1) {
            r1 += __shfl_xor(r1, off);
            r2 += __shfl_xor(r2, off);
        }
        if (lane == 0) {
            s2s[n] = r1;
            s2d[n] = r2;
        }
    }
}

// ---------------- layer-2: att2 inline; 8-edge x 8-lane class-interleave ----------------

__global__ __launch_bounds__(256) void k_l2(const int* __restrict__ rowptr, const int* __restrict__ csr,
                                            const float* __restrict__ s2s, const float* __restrict__ s2d,
                                            const float* __restrict__ Wh2, float* __restrict__ out) {
    int t = threadIdx.x;
    int wv = t >> 6, lane = t & 63;
    int n = blockIdx.x * 4 + wv;
    int base = rowptr[n], deg = rowptr[n + 1] - base;
    float sdw = s2d[n];

    // pass 1: max over edges (64-way)
    float mx = -INFINITY;
    for (int i = lane; i < deg; i += 64) {
        int s = csr[base + i];
        float e = s2s[s] + sdw;
        e = e > 0.f ? e : ALPHA * e;
        mx = fmaxf(mx, e);
    }
    for (int o = 32; o; o >>= 1) mx = fmaxf(mx, __shfl_xor(mx, o));

    // pass 2: 8 edges in flight; lane accumulates classes c8+8q
    int e8 = lane >> 3, c8 = lane & 7;
    float acc0 = 0.f, acc1 = 0.f, acc2 = 0.f, acc3 = 0.f, acc4 = 0.f;
    float smp = 0.f;
    for (int i = e8; i < deg; i += 8) {
        int s = csr[base + i];
        float e = s2s[s] + sdw;
        e = e > 0.f ? e : ALPHA * e;
        float a = expf(e - mx);
        smp += a;
        const float* wp = Wh2 + (size_t)s * 40 + c8;
        acc0 += a * wp[0];
        acc1 += a * wp[8];
        acc2 += a * wp[16];
        acc3 += a * wp[24];
        acc4 += a * wp[32];
    }
    for (int o = 8; o < 64; o <<= 1) {
        smp += __shfl_xor(smp, o);
        acc0 += __shfl_xor(acc0, o);
        acc1 += __shfl_xor(acc1, o);
        acc2 += __shfl_xor(acc2, o);
        acc3 += __shfl_xor(acc3, o);
        acc4 += __shfl_xor(acc4, o);
    }
    float inv = (deg > 0) ? 1.f / smp : 0.f;
    acc0 *= inv; acc1 *= inv; acc2 *= inv; acc3 *= inv; acc4 *= inv;

    // log_softmax over 40 classes (reduce across c8: masks 1,2,4)
    float mv = fmaxf(fmaxf(fmaxf(acc0, acc1), fmaxf(acc2, acc3)), acc4);
    for (int o = 1; o < 8; o <<= 1) mv = fmaxf(mv, __shfl_xor(mv, o));
    float se = expf(acc0 - mv) + expf(acc1 - mv) + expf(acc2 - mv) +
               expf(acc3 - mv) + expf(acc4 - mv);
    for (int o = 1; o < 8; o <<= 1) se += __shfl_xor(se, o);
    float lse = logf(se);
    if (e8 == 0) {
        float* op = out + (size_t)n * 40 + c8;
        op[0]  = acc0 - mv - lse;
        op[8]  = acc1 - mv - lse;
        op[16] = acc2 - mv - lse;
        op[24] = acc3 - mv - lse;
        op[32] = acc4 - mv - lse;
    }
}

// ---------------- host ----------------

extern "C" void kernel_launch(void* const* d_in, const int* in_sizes, int n_in,
                              void* d_out, int out_size, void* d_ws, size_t ws_size,
                              hipStream_t stream) {
    const float* h   = (const float*)d_in[0];
    const int*   ei  = (const int*)d_in[1];
    const float* Whd = (const float*)d_in[2];
    const float* ah  = (const float*)d_in[3];
    const float* Wo  = (const float*)d_in[4];
    const float* ao  = (const float*)d_in[5];
    float* out = (float*)d_out;

    const int* src = ei;
    const int* dst = ei + E_;
    const int nchunks = (N_ + 1023) / 1024;

    char* ws = (char*)d_ws;
    size_t off = 0;
    auto alloc = [&](size_t bytes) -> char* {
        size_t a = (off + 255) & ~(size_t)255;
        off = a + bytes;
        return ws + a;
    };
    int* rowptr = (int*)alloc((size_t)(N_ + 1) * 4);
    int* cursor = (int*)alloc((size_t)N_ * 4);
    int* deg    = (int*)alloc((size_t)N_ * 4);
    int* part   = (int*)alloc((size_t)(nchunks + 1) * 4);
    int* csr    = (int*)alloc((size_t)E_ * 4);
    float* s1s  = (float*)alloc((size_t)N_ * 4 * 4);
    float* s1d  = (float*)alloc((size_t)N_ * 4 * 4);
    float* sinv1= (float*)alloc((size_t)N_ * 4 * 4);
    float* Wh2  = (float*)alloc((size_t)N_ * 40 * 4);
    float* s2s  = (float*)alloc((size_t)N_ * 4);
    float* s2d  = (float*)alloc((size_t)N_ * 4);
    __bf16* Bh  = (__bf16*)alloc((size_t)8 * 272 * 32 * 2);   // 136 KB
    __bf16* Bl  = (__bf16*)alloc((size_t)8 * 272 * 32 * 2);
    float* att1 = (float*)alloc((size_t)E_ * 4 * 4);               // 25.6 MB
    unsigned short* Wh1h = (unsigned short*)alloc((size_t)N_ * 256 * 2); // 51.2 MB
    size_t need = off + 256;                                        // ~106 MB total

    if (ws_size < need) {
        k_sent<<<(int)((OUTEL + 255) / 256), 256, 0, stream>>>(out, OUTEL, -2.0f);
        return;
    }

    // B prep (independent of CSR)
    k_prepB<<<256, 320, 0, stream>>>(Whd, ah, Bh, Bl);

    // CSR build
    k_zero<<<(N_ + 255) / 256, 256, 0, stream>>>(deg, N_);
    k_count<<<(E_ + 255) / 256, 256, 0, stream>>>(dst, deg);
    k_partial<<<nchunks, 256, 0, stream>>>(deg, part);
    k_scan_part<<<1, 128, 0, stream>>>(part, nchunks, rowptr);
    k_scan_final<<<nchunks, 256, 0, stream>>>(deg, part, rowptr, cursor);
    k_fill<<<(E_ + 255) / 256, 256, 0, stream>>>(src, dst, cursor, csr);

    // layer 1: MFMA GEMM (fp16 Wh1 + f32 s1 scores), att1 (2 passes, unnormalized + sinv1)
    k_gemm1m<<<(N_ + 63) / 64, 256, 0, stream>>>(h, Bh, Bl, Wh1h, s1s, s1d);
    k_att1<<<N_ / 4, 256, 0, stream>>>(rowptr, csr, s1s, s1d, att1, sinv1);

    // fused aggregate + normalize + ELU + gemm2 + s2 scores (persistent)
    k_agg1g<<<AGG_BLOCKS, 1024, 0, stream>>>(rowptr, csr, att1, sinv1, Wh1h, Wo, ao, Wh2, s2s, s2d);

    // layer 2 (att2 + denominator fused; 8-edge ILP, coalesced Wh2 reads)
    k_l2<<<N_ / 4, 256, 0, stream>>>(rowptr, csr, s2s, s2d, Wh2, out);
}

// Round 10
// 728.735 us; speedup vs baseline: 3.0840x; 1.0565x over previous
//
#include <hip/hip_runtime.h>

// GAT: N=100000 E=1600000 NFEAT=256 NHID=64 NHEADS=4 NCLASS=40 (hardcoded dims).
// r18 bench attempt failed on infra (container acquisition), not kernel; source
// audited (OOB/alignment/indexing/workspace) and resubmitted unchanged.
// Theory (from r17, 770us): agg1g is op-count bound: fused GEMM2 tail = 576
// wave-inst/node (~3x gather cost) + gather issues same # loads after fp16.
// r18: (1) tail stripped out of agg1g -> new k_gemm2m (MFMA bf16-split, mirrors
// gemm1m; s2 folded as B-columns Wo@ao); agg1g = pure gather, ZERO LDS, writes
// x f32. (2) gather: ushort8 16B/lane, 2 edges/wave-step (half=lane>>5) ->
// half the memory ops; combine via one shfl_xor(32) set per node.

#define ALPHA 0.2f
constexpr int N_ = 100000;
constexpr int E_ = 1600000;
constexpr long OUTEL = (long)N_ * 40;

typedef __bf16 bf16x8 __attribute__((ext_vector_type(8)));
typedef float f32x4 __attribute__((ext_vector_type(4)));
typedef unsigned short u16x8 __attribute__((ext_vector_type(8)));

__device__ __forceinline__ unsigned short f2h(float f) {
    _Float16 h = (_Float16)f;
    return *(unsigned short*)&h;
}
__device__ __forceinline__ float h2f(unsigned short u) {
    _Float16 h = *(_Float16*)&u;
    return (float)h;
}

__global__ void k_sent(float* out, long n, float v) {
    long i = blockIdx.x * 256L + threadIdx.x;
    if (i < n) out[i] = v;
}

// ---------------- CSR build ----------------

__global__ void k_zero(int* p, int n) {
    int i = blockIdx.x * 256 + threadIdx.x;
    if (i < n) p[i] = 0;
}

__global__ void k_count(const int* __restrict__ dst, int* __restrict__ deg) {
    int e = blockIdx.x * 256 + threadIdx.x;
    if (e < E_) {
        int d = dst[e];
        if ((unsigned)d < (unsigned)N_) atomicAdd(&deg[d], 1);
    }
}

__global__ void k_partial(const int* __restrict__ deg, int* __restrict__ part) {
    __shared__ int sd[256];
    int b = blockIdx.x, t = threadIdx.x;
    int base = b * 1024;
    int s = 0;
    for (int i = 0; i < 4; i++) {
        int idx = base + t * 4 + i;
        if (idx < N_) s += deg[idx];
    }
    sd[t] = s;
    __syncthreads();
    for (int o = 128; o; o >>= 1) {
        if (t < o) sd[t] += sd[t + o];
        __syncthreads();
    }
    if (t == 0) part[b] = sd[0];
}

// parallel exclusive scan over nchunks (<=128) partials; total -> rowptr[N_]
__global__ void k_scan_part(int* part, int nchunks, int* rowptr) {
    __shared__ int sd[128];
    int t = threadIdx.x;
    int v = (t < nchunks) ? part[t] : 0;
    sd[t] = v;
    __syncthreads();
    for (int o = 1; o < 128; o <<= 1) {
        int add = (t >= o) ? sd[t - o] : 0;
        __syncthreads();
        sd[t] += add;
        __syncthreads();
    }
    if (t < nchunks) part[t] = sd[t] - v;   // exclusive
    if (t == 127) rowptr[N_] = sd[127];     // total
}

__global__ void k_scan_final(const int* __restrict__ deg, const int* __restrict__ part,
                             int* __restrict__ rowptr, int* __restrict__ cursor) {
    __shared__ int sd[256];
    int b = blockIdx.x, t = threadIdx.x;
    int base = b * 1024;
    int v[4];
    int s = 0;
    for (int i = 0; i < 4; i++) {
        int idx = base + t * 4 + i;
        v[i] = (idx < N_) ? deg[idx] : 0;
        s += v[i];
    }
    sd[t] = s;
    __syncthreads();
    for (int o = 1; o < 256; o <<= 1) {
        int add = (t >= o) ? sd[t - o] : 0;
        __syncthreads();
        sd[t] += add;
        __syncthreads();
    }
    int off0 = part[b] + (sd[t] - s);
    for (int i = 0; i < 4; i++) {
        int idx = base + t * 4 + i;
        if (idx < N_) {
            rowptr[idx] = off0;
            cursor[idx] = off0;
            off0 += v[i];
        }
    }
}

__global__ void k_fill(const int* __restrict__ src, const int* __restrict__ dst,
                       int* __restrict__ cursor, int* __restrict__ csr) {
    int e = blockIdx.x * 256 + threadIdx.x;
    if (e < E_) {
        int d = dst[e];
        if ((unsigned)d < (unsigned)N_) {
            int p = atomicAdd(&cursor[d], 1);
            if ((unsigned)p < (unsigned)E_) csr[p] = src[e];
        }
    }
}

// ---------------- B preps: transpose + bf16 hi/lo split ----------------

__global__ __launch_bounds__(320) void k_prepB(const float* __restrict__ Whd,
                                               const float* __restrict__ ah,
                                               __bf16* __restrict__ Bh, __bf16* __restrict__ Bl) {
    int k = blockIdx.x;      // 0..255
    int c = threadIdx.x;     // 0..319
    if (c >= 272) return;
    float v = 0.f;
    if (c < 256) {
        v = Whd[(c >> 6) * 16384 + k * 64 + (c & 63)];
    } else if (c < 264) {
        int hh = (c - 256) & 3;
        int isd = (c >= 260) ? 64 : 0;
        const float* wp = Whd + hh * 16384 + k * 64;
        const float* ap = ah + hh * 128 + isd;
        float s = 0.f;
        for (int j = 0; j < 64; j++) s += wp[j] * ap[j];
        v = s;
    }
    __bf16 hi = (__bf16)v;
    __bf16 lo = (__bf16)(v - (float)hi);
    size_t idx = ((size_t)(k >> 5) * 272 + c) * 32 + (k & 31);
    Bh[idx] = hi;
    Bl[idx] = lo;
}

// Wo (256x40) + s2 columns (Wo@ao_s, Wo@ao_d) -> 48-col bf16 hi/lo, K-chunked.
__global__ __launch_bounds__(64) void k_prepB2(const float* __restrict__ Wo,
                                               const float* __restrict__ ao,
                                               __bf16* __restrict__ Boh, __bf16* __restrict__ Bol) {
    int k = blockIdx.x;      // 0..255
    int c = threadIdx.x;     // 0..63
    if (c >= 48) return;
    float v = 0.f;
    if (c < 40) {
        v = Wo[k * 40 + c];
    } else if (c < 42) {
        const float* ap = ao + (c - 40) * 40;
        float s = 0.f;
        for (int j = 0; j < 40; j++) s += Wo[k * 40 + j] * ap[j];
        v = s;
    }
    __bf16 hi = (__bf16)v;
    __bf16 lo = (__bf16)(v - (float)hi);
    size_t idx = ((size_t)(k >> 5) * 48 + c) * 32 + (k & 31);
    Boh[idx] = hi;
    Bol[idx] = lo;
}

// ---------------- GEMM1 via MFMA 16x16x32 bf16, split-precision (3 terms).
// Wh1 output stored fp16 (sole consumer is the agg1g gather). s1 scores f32.

__global__ __launch_bounds__(256) void k_gemm1m(const float* __restrict__ h,
                                                const __bf16* __restrict__ Bh,
                                                const __bf16* __restrict__ Bl,
                                                unsigned short* __restrict__ Wh1h,
                                                float* __restrict__ s1s,
                                                float* __restrict__ s1d) {
    int t = threadIdx.x;
    int wv = t >> 6, l = t & 63;
    int l15 = l & 15, lg = l >> 4;
    int rowA = blockIdx.x * 64 + wv * 16 + l15;
    bool rok = rowA < N_;
    const float* hp = h + (size_t)rowA * 256 + lg * 8;

    f32x4 acc[17];
#pragma unroll
    for (int i = 0; i < 17; i++) acc[i] = (f32x4){0.f, 0.f, 0.f, 0.f};

    for (int kc = 0; kc < 8; kc++) {
        float va[8] = {0.f, 0.f, 0.f, 0.f, 0.f, 0.f, 0.f, 0.f};
        if (rok) {
            float4 p = *(const float4*)(hp + kc * 32);
            float4 q = *(const float4*)(hp + kc * 32 + 4);
            va[0] = p.x; va[1] = p.y; va[2] = p.z; va[3] = p.w;
            va[4] = q.x; va[5] = q.y; va[6] = q.z; va[7] = q.w;
        }
        bf16x8 ahi, alo;
#pragma unroll
        for (int j = 0; j < 8; j++) {
            __bf16 hi = (__bf16)va[j];
            ahi[j] = hi;
            alo[j] = (__bf16)(va[j] - (float)hi);
        }
        const __bf16* bph = Bh + ((size_t)kc * 272 + l15) * 32 + lg * 8;
        const __bf16* bpl = Bl + ((size_t)kc * 272 + l15) * 32 + lg * 8;
#pragma unroll
        for (int tt = 0; tt < 17; tt++) {
            bf16x8 bh = *(const bf16x8*)(bph + tt * 512);
            bf16x8 bl = *(const bf16x8*)(bpl + tt * 512);
            acc[tt] = __builtin_amdgcn_mfma_f32_16x16x32_bf16(ahi, bh, acc[tt], 0, 0, 0);
            acc[tt] = __builtin_amdgcn_mfma_f32_16x16x32_bf16(alo, bh, acc[tt], 0, 0, 0);
            acc[tt] = __builtin_amdgcn_mfma_f32_16x16x32_bf16(ahi, bl, acc[tt], 0, 0, 0);
        }
    }

    int rowD0 = blockIdx.x * 64 + wv * 16 + lg * 4;
#pragma unroll
    for (int tt = 0; tt < 16; tt++) {
#pragma unroll
        for (int r = 0; r < 4; r++) {
            int orow = rowD0 + r;
            if (orow < N_) Wh1h[(size_t)orow * 256 + tt * 16 + l15] = f2h(acc[tt][r]);
        }
    }
#pragma unroll
    for (int r = 0; r < 4; r++) {
        int orow = rowD0 + r;
        if (orow < N_) {
            if (l15 < 4) s1s[orow * 4 + l15] = acc[16][r];
            else if (l15 < 8) s1d[orow * 4 + (l15 - 4)] = acc[16][r];
        }
    }
}

// ---------------- att1: 2 gather passes; writes UNNORMALIZED exp + sinv1 ----------------

__global__ __launch_bounds__(256) void k_att1(const int* __restrict__ rowptr, const int* __restrict__ csr,
                                              const float* __restrict__ s1s, const float* __restrict__ s1d,
                                              float* __restrict__ att1, float* __restrict__ sinv1) {
    int t = threadIdx.x;
    int wv = t >> 6, l = t & 63;
    int n = blockIdx.x * 4 + wv;
    int base = rowptr[n], deg = rowptr[n + 1] - base;
    int i = l >> 2, hh = l & 3;
    float sdw = s1d[n * 4 + hh];

    float mx = -INFINITY;
    for (int ib = 0; ib < deg; ib += 16) {
        int e = ib + i;
        if (e < deg) {
            int s = csr[base + e];
            float v = s1s[s * 4 + hh] + sdw;
            v = v > 0.f ? v : ALPHA * v;
            mx = fmaxf(mx, v);
        }
    }
    for (int o = 4; o < 64; o <<= 1) mx = fmaxf(mx, __shfl_xor(mx, o));
    float sm = 0.f;
    for (int ib = 0; ib < deg; ib += 16) {
        int e = ib + i;
        if (e < deg) {
            int s = csr[base + e];
            float v = s1s[s * 4 + hh] + sdw;
            v = v > 0.f ? v : ALPHA * v;
            float ex = expf(v - mx);
            att1[(size_t)(base + e) * 4 + hh] = ex;   // unnormalized
            sm += ex;
        }
    }
    for (int o = 4; o < 64; o <<= 1) sm += __shfl_xor(sm, o);
    if (l < 4) sinv1[n * 4 + hh] = (deg > 0) ? 1.f / sm : 0.f;
}

// ---------------- layer-1 aggregate: PURE gather + normalize + ELU -> x (f32).
// ZERO LDS. Persistent 512x1024. Lane layout: half = lane>>5 (which edge of a
// pair), lh = lane&31 owns 8 fp16 feats (16B ushort8 load) -> 2 edges/wave-step,
// HALF the memory ops of the 4-feat layout. Combine halves via shfl_xor(32).

constexpr int AGG_BLOCKS = 512;
constexpr int AGG_WAVES = 16;
constexpr int NODES_PER_SWEEP = AGG_BLOCKS * AGG_WAVES;

__global__ __launch_bounds__(1024) void k_agg1g(const int* __restrict__ rowptr, const int* __restrict__ csr,
                                                const float* __restrict__ att1, const float* __restrict__ sinv1,
                                                const unsigned short* __restrict__ Wh1h,
                                                float* __restrict__ x) {
    int t = threadIdx.x;
    int w = t >> 6, lane = t & 63;
    int half = lane >> 5;          // which edge of the pair
    int lh = lane & 31;            // feature-group owner: feats lh*8 .. +8
    int f8 = lh << 3;
    int hw = lh >> 3;              // head (8 feats never cross a 64-block)

    for (int n = blockIdx.x * AGG_WAVES + w; n < N_; n += NODES_PER_SWEEP) {
        int base = rowptr[n], deg = rowptr[n + 1] - base;

        float acc[8] = {0.f, 0.f, 0.f, 0.f, 0.f, 0.f, 0.f, 0.f};
        int i = 0;
        // 4 edges per iteration (2 pairs), each lane: 2x 16B gathers
        for (; i + 3 < deg; i += 4) {
            int b0 = base + i;
            int sA = csr[b0 + half];
            int sB = csr[b0 + 2 + half];
            float atA = att1[(size_t)(b0 + half) * 4 + hw];
            float atB = att1[(size_t)(b0 + 2 + half) * 4 + hw];
            u16x8 uA = *(const u16x8*)(Wh1h + (size_t)sA * 256 + f8);
            u16x8 uB = *(const u16x8*)(Wh1h + (size_t)sB * 256 + f8);
#pragma unroll
            for (int j = 0; j < 8; j++)
                acc[j] += atA * h2f(uA[j]) + atB * h2f(uB[j]);
        }
        // remainder pairs (1-3 edges); phantom edge masked with at=0
        for (; i < deg; i += 2) {
            int b0 = base + i;
            int e = i + half;
            bool ok = e < deg;
            int sA = csr[b0 + (ok ? half : 0)];
            float atA = ok ? att1[(size_t)(b0 + half) * 4 + hw] : 0.f;
            u16x8 uA = *(const u16x8*)(Wh1h + (size_t)sA * 256 + f8);
#pragma unroll
            for (int j = 0; j < 8; j++)
                acc[j] += atA * h2f(uA[j]);
        }
        // combine even/odd-edge halves (lane ^ 32 holds the partner partial)
#pragma unroll
        for (int j = 0; j < 8; j++) acc[j] += __shfl_xor(acc[j], 32);

        // normalize + ELU + store: this lane writes 4 of its 8 feats
        float inv = sinv1[n * 4 + hw];
        int jo = half * 4;
        float4 o;
        o.x = acc[jo + 0] * inv; o.y = acc[jo + 1] * inv;
        o.z = acc[jo + 2] * inv; o.w = acc[jo + 3] * inv;
        o.x = o.x > 0.f ? o.x : (expf(o.x) - 1.f);
        o.y = o.y > 0.f ? o.y : (expf(o.y) - 1.f);
        o.z = o.z > 0.f ? o.z : (expf(o.z) - 1.f);
        o.w = o.w > 0.f ? o.w : (expf(o.w) - 1.f);
        *(float4*)(x + (size_t)n * 256 + f8 + jo) = o;
    }
}

// ---------------- GEMM2 via MFMA (mirrors gemm1m): x(f32->bf16 split) @ Bo.
// 48 cols = 40 Wh2 + s2s (col 40) + s2d (col 41) + 6 pad.

__global__ __launch_bounds__(256) void k_gemm2m(const float* __restrict__ x,
                                                const __bf16* __restrict__ Boh,
                                                const __bf16* __restrict__ Bol,
                                                float* __restrict__ Wh2,
                                                float* __restrict__ s2s,
                                                float* __restrict__ s2d) {
    int t = threadIdx.x;
    int wv = t >> 6, l = t & 63;
    int l15 = l & 15, lg = l >> 4;
    int rowA = blockIdx.x * 64 + wv * 16 + l15;
    bool rok = rowA < N_;
    const float* xp = x + (size_t)rowA * 256 + lg * 8;

    f32x4 acc[3];
#pragma unroll
    for (int i = 0; i < 3; i++) acc[i] = (f32x4){0.f, 0.f, 0.f, 0.f};

    for (int kc = 0; kc < 8; kc++) {
        float va[8] = {0.f, 0.f, 0.f, 0.f, 0.f, 0.f, 0.f, 0.f};
        if (rok) {
            float4 p = *(const float4*)(xp + kc * 32);
            float4 q = *(const float4*)(xp + kc * 32 + 4);
            va[0] = p.x; va[1] = p.y; va[2] = p.z; va[3] = p.w;
            va[4] = q.x; va[5] = q.y; va[6] = q.z; va[7] = q.w;
        }
        bf16x8 ahi, alo;
#pragma unroll
        for (int j = 0; j < 8; j++) {
            __bf16 hi = (__bf16)va[j];
            ahi[j] = hi;
            alo[j] = (__bf16)(va[j] - (float)hi);
        }
        const __bf16* bph = Boh + ((size_t)kc * 48 + l15) * 32 + lg * 8;
        const __bf16* bpl = Bol + ((size_t)kc * 48 + l15) * 32 + lg * 8;
#pragma unroll
        for (int tt = 0; tt < 3; tt++) {
            bf16x8 bh = *(const bf16x8*)(bph + tt * 512);
            bf16x8 bl = *(const bf16x8*)(bpl + tt * 512);
            acc[tt] = __builtin_amdgcn_mfma_f32_16x16x32_bf16(ahi, bh, acc[tt], 0, 0, 0);
            acc[tt] = __builtin_amdgcn_mfma_f32_16x16x32_bf16(alo, bh, acc[tt], 0, 0, 0);
            acc[tt] = __builtin_amdgcn_mfma_f32_16x16x32_bf16(ahi, bl, acc[tt], 0, 0, 0);
        }
    }

    int rowD0 = blockIdx.x * 64 + wv * 16 + lg * 4;
#pragma unroll
    for (int tt = 0; tt < 3; tt++) {
        int col = tt * 16 + l15;
#pragma unroll
        for (int r = 0; r < 4; r++) {
            int orow = rowD0 + r;
            if (orow < N_) {
                if (col < 40) Wh2[(size_t)orow * 40 + col] = acc[tt][r];
                else if (col == 40) s2s[orow] = acc[tt][r];
                else if (col == 41) s2d[orow] = acc[tt][r];
            }
        }
    }
}

// ---------------- layer-2: att2 inline; 8-edge x 8-lane class-interleave ----------------

__global__ __launch_bounds__(256) void k_l2(const int* __restrict__ rowptr, const int* __restrict__ csr,
                                            const float* __restrict__ s2s, const float* __restrict__ s2d,
                                            const float* __restrict__ Wh2, float* __restrict__ out) {
    int t = threadIdx.x;
    int wv = t >> 6, lane = t & 63;
    int n = blockIdx.x * 4 + wv;
    int base = rowptr[n], deg = rowptr[n + 1] - base;
    float sdw = s2d[n];

    // pass 1: max over edges (64-way)
    float mx = -INFINITY;
    for (int i = lane; i < deg; i += 64) {
        int s = csr[base + i];
        float e = s2s[s] + sdw;
        e = e > 0.f ? e : ALPHA * e;
        mx = fmaxf(mx, e);
    }
    for (int o = 32; o; o >>= 1) mx = fmaxf(mx, __shfl_xor(mx, o));

    // pass 2: 8 edges in flight; lane accumulates classes c8+8q
    int e8 = lane >> 3, c8 = lane & 7;
    float acc0 = 0.f, acc1 = 0.f, acc2 = 0.f, acc3 = 0.f, acc4 = 0.f;
    float smp = 0.f;
    for (int i = e8; i < deg; i += 8) {
        int s = csr[base + i];
        float e = s2s[s] + sdw;
        e = e > 0.f ? e : ALPHA * e;
        float a = expf(e - mx);
        smp += a;
        const float* wp = Wh2 + (size_t)s * 40 + c8;
        acc0 += a * wp[0];
        acc1 += a * wp[8];
        acc2 += a * wp[16];
        acc3 += a * wp[24];
        acc4 += a * wp[32];
    }
    for (int o = 8; o < 64; o <<= 1) {
        smp += __shfl_xor(smp, o);
        acc0 += __shfl_xor(acc0, o);
        acc1 += __shfl_xor(acc1, o);
        acc2 += __shfl_xor(acc2, o);
        acc3 += __shfl_xor(acc3, o);
        acc4 += __shfl_xor(acc4, o);
    }
    float inv = (deg > 0) ? 1.f / smp : 0.f;
    acc0 *= inv; acc1 *= inv; acc2 *= inv; acc3 *= inv; acc4 *= inv;

    // log_softmax over 40 classes (reduce across c8: masks 1,2,4)
    float mv = fmaxf(fmaxf(fmaxf(acc0, acc1), fmaxf(acc2, acc3)), acc4);
    for (int o = 1; o < 8; o <<= 1) mv = fmaxf(mv, __shfl_xor(mv, o));
    float se = expf(acc0 - mv) + expf(acc1 - mv) + expf(acc2 - mv) +
               expf(acc3 - mv) + expf(acc4 - mv);
    for (int o = 1; o < 8; o <<= 1) se += __shfl_xor(se, o);
    float lse = logf(se);
    if (e8 == 0) {
        float* op = out + (size_t)n * 40 + c8;
        op[0]  = acc0 - mv - lse;
        op[8]  = acc1 - mv - lse;
        op[16] = acc2 - mv - lse;
        op[24] = acc3 - mv - lse;
        op[32] = acc4 - mv - lse;
    }
}

// ---------------- host ----------------

extern "C" void kernel_launch(void* const* d_in, const int* in_sizes, int n_in,
                              void* d_out, int out_size, void* d_ws, size_t ws_size,
                              hipStream_t stream) {
    const float* h   = (const float*)d_in[0];
    const int*   ei  = (const int*)d_in[1];
    const float* Whd = (const float*)d_in[2];
    const float* ah  = (const float*)d_in[3];
    const float* Wo  = (const float*)d_in[4];
    const float* ao  = (const float*)d_in[5];
    float* out = (float*)d_out;

    const int* src = ei;
    const int* dst = ei + E_;
    const int nchunks = (N_ + 1023) / 1024;

    char* ws = (char*)d_ws;
    size_t off = 0;
    auto alloc = [&](size_t bytes) -> char* {
        size_t a = (off + 255) & ~(size_t)255;
        off = a + bytes;
        return ws + a;
    };
    int* rowptr = (int*)alloc((size_t)(N_ + 1) * 4);
    int* cursor = (int*)alloc((size_t)N_ * 4);
    int* deg    = (int*)alloc((size_t)N_ * 4);
    int* part   = (int*)alloc((size_t)(nchunks + 1) * 4);
    int* csr    = (int*)alloc((size_t)E_ * 4);
    float* s1s  = (float*)alloc((size_t)N_ * 4 * 4);
    float* s1d  = (float*)alloc((size_t)N_ * 4 * 4);
    float* sinv1= (float*)alloc((size_t)N_ * 4 * 4);
    float* Wh2  = (float*)alloc((size_t)N_ * 40 * 4);
    float* s2s  = (float*)alloc((size_t)N_ * 4);
    float* s2d  = (float*)alloc((size_t)N_ * 4);
    __bf16* Bh  = (__bf16*)alloc((size_t)8 * 272 * 32 * 2);   // 136 KB
    __bf16* Bl  = (__bf16*)alloc((size_t)8 * 272 * 32 * 2);
    __bf16* Boh = (__bf16*)alloc((size_t)8 * 48 * 32 * 2);    // 24.6 KB
    __bf16* Bol = (__bf16*)alloc((size_t)8 * 48 * 32 * 2);
    float* att1 = (float*)alloc((size_t)E_ * 4 * 4);               // 25.6 MB
    unsigned short* Wh1h = (unsigned short*)alloc((size_t)N_ * 256 * 2); // 51.2 MB
    float* x    = (float*)alloc((size_t)N_ * 256 * 4);             // 102.4 MB
    size_t need = off + 256;                                        // ~208 MB total

    if (ws_size < need) {
        k_sent<<<(int)((OUTEL + 255) / 256), 256, 0, stream>>>(out, OUTEL, -2.0f);
        return;
    }

    // B preps (independent of CSR)
    k_prepB<<<256, 320, 0, stream>>>(Whd, ah, Bh, Bl);
    k_prepB2<<<256, 64, 0, stream>>>(Wo, ao, Boh, Bol);

    // CSR build
    k_zero<<<(N_ + 255) / 256, 256, 0, stream>>>(deg, N_);
    k_count<<<(E_ + 255) / 256, 256, 0, stream>>>(dst, deg);
    k_partial<<<nchunks, 256, 0, stream>>>(deg, part);
    k_scan_part<<<1, 128, 0, stream>>>(part, nchunks, rowptr);
    k_scan_final<<<nchunks, 256, 0, stream>>>(deg, part, rowptr, cursor);
    k_fill<<<(E_ + 255) / 256, 256, 0, stream>>>(src, dst, cursor, csr);

    // layer 1: MFMA GEMM (fp16 Wh1 + f32 s1 scores), att1 (2 passes)
    k_gemm1m<<<(N_ + 63) / 64, 256, 0, stream>>>(h, Bh, Bl, Wh1h, s1s, s1d);
    k_att1<<<N_ / 4, 256, 0, stream>>>(rowptr, csr, s1s, s1d, att1, sinv1);

    // pure gather aggregate -> x (f32)
    k_agg1g<<<AGG_BLOCKS, 1024, 0, stream>>>(rowptr, csr, att1, sinv1, Wh1h, x);

    // GEMM2 via MFMA (Wh2 + s2 scores folded as B-columns)
    k_gemm2m<<<(N_ + 63) / 64, 256, 0, stream>>>(x, Boh, Bol, Wh2, s2s, s2d);

    // layer 2 (att2 + denominator fused; 8-edge ILP, coalesced Wh2 reads)
    k_l2<<<N_ / 4, 256, 0, stream>>>(rowptr, csr, s2s, s2d, Wh2, out);
}

// Round 11
// 726.912 us; speedup vs baseline: 3.0918x; 1.0025x over previous
//
#include <hip/hip_runtime.h>

// GAT: N=100000 E=1600000 NFEAT=256 NHID=64 NHEADS=4 NCLASS=40 (hardcoded dims).
// r18 (729us): gemm1m is new #1 at 151us — VGPR=80 (acc=68) leaves ~12 regs for
// B-tile pipelining -> each of 34 L2 tile-loads/kc exposes ~250cy latency
// (MfmaUtil 10.7%, HBM 9%: pure latency-bound). MFMA floor is ~5us.
// r19: gemm1m only — __launch_bounds__(256,1) (RELAX reg budget; r13's spill
// was from TIGHTENING) + explicit bhv[17]/blv[17] prefetch arrays, fully
// unrolled (static idx): all 34 loads/kc in flight under counted vmcnt.
// VGPR ~230 expected, no spill. All else identical to r18.

#define ALPHA 0.2f
constexpr int N_ = 100000;
constexpr int E_ = 1600000;
constexpr long OUTEL = (long)N_ * 40;

typedef __bf16 bf16x8 __attribute__((ext_vector_type(8)));
typedef float f32x4 __attribute__((ext_vector_type(4)));
typedef unsigned short u16x8 __attribute__((ext_vector_type(8)));

__device__ __forceinline__ unsigned short f2h(float f) {
    _Float16 h = (_Float16)f;
    return *(unsigned short*)&h;
}
__device__ __forceinline__ float h2f(unsigned short u) {
    _Float16 h = *(_Float16*)&u;
    return (float)h;
}

__global__ void k_sent(float* out, long n, float v) {
    long i = blockIdx.x * 256L + threadIdx.x;
    if (i < n) out[i] = v;
}

// ---------------- CSR build ----------------

__global__ void k_zero(int* p, int n) {
    int i = blockIdx.x * 256 + threadIdx.x;
    if (i < n) p[i] = 0;
}

__global__ void k_count(const int* __restrict__ dst, int* __restrict__ deg) {
    int e = blockIdx.x * 256 + threadIdx.x;
    if (e < E_) {
        int d = dst[e];
        if ((unsigned)d < (unsigned)N_) atomicAdd(&deg[d], 1);
    }
}

__global__ void k_partial(const int* __restrict__ deg, int* __restrict__ part) {
    __shared__ int sd[256];
    int b = blockIdx.x, t = threadIdx.x;
    int base = b * 1024;
    int s = 0;
    for (int i = 0; i < 4; i++) {
        int idx = base + t * 4 + i;
        if (idx < N_) s += deg[idx];
    }
    sd[t] = s;
    __syncthreads();
    for (int o = 128; o; o >>= 1) {
        if (t < o) sd[t] += sd[t + o];
        __syncthreads();
    }
    if (t == 0) part[b] = sd[0];
}

// parallel exclusive scan over nchunks (<=128) partials; total -> rowptr[N_]
__global__ void k_scan_part(int* part, int nchunks, int* rowptr) {
    __shared__ int sd[128];
    int t = threadIdx.x;
    int v = (t < nchunks) ? part[t] : 0;
    sd[t] = v;
    __syncthreads();
    for (int o = 1; o < 128; o <<= 1) {
        int add = (t >= o) ? sd[t - o] : 0;
        __syncthreads();
        sd[t] += add;
        __syncthreads();
    }
    if (t < nchunks) part[t] = sd[t] - v;   // exclusive
    if (t == 127) rowptr[N_] = sd[127];     // total
}

__global__ void k_scan_final(const int* __restrict__ deg, const int* __restrict__ part,
                             int* __restrict__ rowptr, int* __restrict__ cursor) {
    __shared__ int sd[256];
    int b = blockIdx.x, t = threadIdx.x;
    int base = b * 1024;
    int v[4];
    int s = 0;
    for (int i = 0; i < 4; i++) {
        int idx = base + t * 4 + i;
        v[i] = (idx < N_) ? deg[idx] : 0;
        s += v[i];
    }
    sd[t] = s;
    __syncthreads();
    for (int o = 1; o < 256; o <<= 1) {
        int add = (t >= o) ? sd[t - o] : 0;
        __syncthreads();
        sd[t] += add;
        __syncthreads();
    }
    int off0 = part[b] + (sd[t] - s);
    for (int i = 0; i < 4; i++) {
        int idx = base + t * 4 + i;
        if (idx < N_) {
            rowptr[idx] = off0;
            cursor[idx] = off0;
            off0 += v[i];
        }
    }
}

__global__ void k_fill(const int* __restrict__ src, const int* __restrict__ dst,
                       int* __restrict__ cursor, int* __restrict__ csr) {
    int e = blockIdx.x * 256 + threadIdx.x;
    if (e < E_) {
        int d = dst[e];
        if ((unsigned)d < (unsigned)N_) {
            int p = atomicAdd(&cursor[d], 1);
            if ((unsigned)p < (unsigned)E_) csr[p] = src[e];
        }
    }
}

// ---------------- B preps: transpose + bf16 hi/lo split ----------------

__global__ __launch_bounds__(320) void k_prepB(const float* __restrict__ Whd,
                                               const float* __restrict__ ah,
                                               __bf16* __restrict__ Bh, __bf16* __restrict__ Bl) {
    int k = blockIdx.x;      // 0..255
    int c = threadIdx.x;     // 0..319
    if (c >= 272) return;
    float v = 0.f;
    if (c < 256) {
        v = Whd[(c >> 6) * 16384 + k * 64 + (c & 63)];
    } else if (c < 264) {
        int hh = (c - 256) & 3;
        int isd = (c >= 260) ? 64 : 0;
        const float* wp = Whd + hh * 16384 + k * 64;
        const float* ap = ah + hh * 128 + isd;
        float s = 0.f;
        for (int j = 0; j < 64; j++) s += wp[j] * ap[j];
        v = s;
    }
    __bf16 hi = (__bf16)v;
    __bf16 lo = (__bf16)(v - (float)hi);
    size_t idx = ((size_t)(k >> 5) * 272 + c) * 32 + (k & 31);
    Bh[idx] = hi;
    Bl[idx] = lo;
}

// Wo (256x40) + s2 columns (Wo@ao_s, Wo@ao_d) -> 48-col bf16 hi/lo, K-chunked.
__global__ __launch_bounds__(64) void k_prepB2(const float* __restrict__ Wo,
                                               const float* __restrict__ ao,
                                               __bf16* __restrict__ Boh, __bf16* __restrict__ Bol) {
    int k = blockIdx.x;      // 0..255
    int c = threadIdx.x;     // 0..63
    if (c >= 48) return;
    float v = 0.f;
    if (c < 40) {
        v = Wo[k * 40 + c];
    } else if (c < 42) {
        const float* ap = ao + (c - 40) * 40;
        float s = 0.f;
        for (int j = 0; j < 40; j++) s += Wo[k * 40 + j] * ap[j];
        v = s;
    }
    __bf16 hi = (__bf16)v;
    __bf16 lo = (__bf16)(v - (float)hi);
    size_t idx = ((size_t)(k >> 5) * 48 + c) * 32 + (k & 31);
    Boh[idx] = hi;
    Bol[idx] = lo;
}

// ---------------- GEMM1 via MFMA 16x16x32 bf16, split-precision (3 terms).
// Wh1 output stored fp16. launch_bounds(256,1): relax VGPR cap so all 34
// B-tiles/kc prefetch into registers (bhv/blv arrays, fully unrolled).

__global__ __launch_bounds__(256, 1) void k_gemm1m(const float* __restrict__ h,
                                                   const __bf16* __restrict__ Bh,
                                                   const __bf16* __restrict__ Bl,
                                                   unsigned short* __restrict__ Wh1h,
                                                   float* __restrict__ s1s,
                                                   float* __restrict__ s1d) {
    int t = threadIdx.x;
    int wv = t >> 6, l = t & 63;
    int l15 = l & 15, lg = l >> 4;
    int rowA = blockIdx.x * 64 + wv * 16 + l15;
    bool rok = rowA < N_;
    const float* hp = h + (size_t)rowA * 256 + lg * 8;

    f32x4 acc[17];
#pragma unroll
    for (int i = 0; i < 17; i++) acc[i] = (f32x4){0.f, 0.f, 0.f, 0.f};

    for (int kc = 0; kc < 8; kc++) {
        float va[8] = {0.f, 0.f, 0.f, 0.f, 0.f, 0.f, 0.f, 0.f};
        if (rok) {
            float4 p = *(const float4*)(hp + kc * 32);
            float4 q = *(const float4*)(hp + kc * 32 + 4);
            va[0] = p.x; va[1] = p.y; va[2] = p.z; va[3] = p.w;
            va[4] = q.x; va[5] = q.y; va[6] = q.z; va[7] = q.w;
        }
        bf16x8 ahi, alo;
#pragma unroll
        for (int j = 0; j < 8; j++) {
            __bf16 hi = (__bf16)va[j];
            ahi[j] = hi;
            alo[j] = (__bf16)(va[j] - (float)hi);
        }
        const __bf16* bph = Bh + ((size_t)kc * 272 + l15) * 32 + lg * 8;
        const __bf16* bpl = Bl + ((size_t)kc * 272 + l15) * 32 + lg * 8;
        // prefetch ALL 34 tiles for this kc (static indices; ~136 VGPR in flight)
        bf16x8 bhv[17], blv[17];
#pragma unroll
        for (int tt = 0; tt < 17; tt++) {
            bhv[tt] = *(const bf16x8*)(bph + tt * 512);
            blv[tt] = *(const bf16x8*)(bpl + tt * 512);
        }
#pragma unroll
        for (int tt = 0; tt < 17; tt++) {
            acc[tt] = __builtin_amdgcn_mfma_f32_16x16x32_bf16(ahi, bhv[tt], acc[tt], 0, 0, 0);
            acc[tt] = __builtin_amdgcn_mfma_f32_16x16x32_bf16(alo, bhv[tt], acc[tt], 0, 0, 0);
            acc[tt] = __builtin_amdgcn_mfma_f32_16x16x32_bf16(ahi, blv[tt], acc[tt], 0, 0, 0);
        }
    }

    int rowD0 = blockIdx.x * 64 + wv * 16 + lg * 4;
#pragma unroll
    for (int tt = 0; tt < 16; tt++) {
#pragma unroll
        for (int r = 0; r < 4; r++) {
            int orow = rowD0 + r;
            if (orow < N_) Wh1h[(size_t)orow * 256 + tt * 16 + l15] = f2h(acc[tt][r]);
        }
    }
#pragma unroll
    for (int r = 0; r < 4; r++) {
        int orow = rowD0 + r;
        if (orow < N_) {
            if (l15 < 4) s1s[orow * 4 + l15] = acc[16][r];
            else if (l15 < 8) s1d[orow * 4 + (l15 - 4)] = acc[16][r];
        }
    }
}

// ---------------- att1: 2 gather passes; writes UNNORMALIZED exp + sinv1 ----------------

__global__ __launch_bounds__(256) void k_att1(const int* __restrict__ rowptr, const int* __restrict__ csr,
                                              const float* __restrict__ s1s, const float* __restrict__ s1d,
                                              float* __restrict__ att1, float* __restrict__ sinv1) {
    int t = threadIdx.x;
    int wv = t >> 6, l = t & 63;
    int n = blockIdx.x * 4 + wv;
    int base = rowptr[n], deg = rowptr[n + 1] - base;
    int i = l >> 2, hh = l & 3;
    float sdw = s1d[n * 4 + hh];

    float mx = -INFINITY;
    for (int ib = 0; ib < deg; ib += 16) {
        int e = ib + i;
        if (e < deg) {
            int s = csr[base + e];
            float v = s1s[s * 4 + hh] + sdw;
            v = v > 0.f ? v : ALPHA * v;
            mx = fmaxf(mx, v);
        }
    }
    for (int o = 4; o < 64; o <<= 1) mx = fmaxf(mx, __shfl_xor(mx, o));
    float sm = 0.f;
    for (int ib = 0; ib < deg; ib += 16) {
        int e = ib + i;
        if (e < deg) {
            int s = csr[base + e];
            float v = s1s[s * 4 + hh] + sdw;
            v = v > 0.f ? v : ALPHA * v;
            float ex = expf(v - mx);
            att1[(size_t)(base + e) * 4 + hh] = ex;   // unnormalized
            sm += ex;
        }
    }
    for (int o = 4; o < 64; o <<= 1) sm += __shfl_xor(sm, o);
    if (l < 4) sinv1[n * 4 + hh] = (deg > 0) ? 1.f / sm : 0.f;
}

// ---------------- layer-1 aggregate: PURE gather + normalize + ELU -> x (f32).
// ZERO LDS. Persistent 512x1024. half = lane>>5, lh = lane&31 owns 8 fp16 feats
// (16B ushort8) -> 2 edges/wave-step. Combine halves via shfl_xor(32).

constexpr int AGG_BLOCKS = 512;
constexpr int AGG_WAVES = 16;
constexpr int NODES_PER_SWEEP = AGG_BLOCKS * AGG_WAVES;

__global__ __launch_bounds__(1024) void k_agg1g(const int* __restrict__ rowptr, const int* __restrict__ csr,
                                                const float* __restrict__ att1, const float* __restrict__ sinv1,
                                                const unsigned short* __restrict__ Wh1h,
                                                float* __restrict__ x) {
    int t = threadIdx.x;
    int w = t >> 6, lane = t & 63;
    int half = lane >> 5;          // which edge of the pair
    int lh = lane & 31;            // feature-group owner: feats lh*8 .. +8
    int f8 = lh << 3;
    int hw = lh >> 3;              // head (8 feats never cross a 64-block)

    for (int n = blockIdx.x * AGG_WAVES + w; n < N_; n += NODES_PER_SWEEP) {
        int base = rowptr[n], deg = rowptr[n + 1] - base;

        float acc[8] = {0.f, 0.f, 0.f, 0.f, 0.f, 0.f, 0.f, 0.f};
        int i = 0;
        // 4 edges per iteration (2 pairs), each lane: 2x 16B gathers
        for (; i + 3 < deg; i += 4) {
            int b0 = base + i;
            int sA = csr[b0 + half];
            int sB = csr[b0 + 2 + half];
            float atA = att1[(size_t)(b0 + half) * 4 + hw];
            float atB = att1[(size_t)(b0 + 2 + half) * 4 + hw];
            u16x8 uA = *(const u16x8*)(Wh1h + (size_t)sA * 256 + f8);
            u16x8 uB = *(const u16x8*)(Wh1h + (size_t)sB * 256 + f8);
#pragma unroll
            for (int j = 0; j < 8; j++)
                acc[j] += atA * h2f(uA[j]) + atB * h2f(uB[j]);
        }
        // remainder pairs (1-3 edges); phantom edge masked with at=0
        for (; i < deg; i += 2) {
            int b0 = base + i;
            int e = i + half;
            bool ok = e < deg;
            int sA = csr[b0 + (ok ? half : 0)];
            float atA = ok ? att1[(size_t)(b0 + half) * 4 + hw] : 0.f;
            u16x8 uA = *(const u16x8*)(Wh1h + (size_t)sA * 256 + f8);
#pragma unroll
            for (int j = 0; j < 8; j++)
                acc[j] += atA * h2f(uA[j]);
        }
        // combine even/odd-edge halves (lane ^ 32 holds the partner partial)
#pragma unroll
        for (int j = 0; j < 8; j++) acc[j] += __shfl_xor(acc[j], 32);

        // normalize + ELU + store: this lane writes 4 of its 8 feats
        float inv = sinv1[n * 4 + hw];
        int jo = half * 4;
        float4 o;
        o.x = acc[jo + 0] * inv; o.y = acc[jo + 1] * inv;
        o.z = acc[jo + 2] * inv; o.w = acc[jo + 3] * inv;
        o.x = o.x > 0.f ? o.x : (expf(o.x) - 1.f);
        o.y = o.y > 0.f ? o.y : (expf(o.y) - 1.f);
        o.z = o.z > 0.f ? o.z : (expf(o.z) - 1.f);
        o.w = o.w > 0.f ? o.w : (expf(o.w) - 1.f);
        *(float4*)(x + (size_t)n * 256 + f8 + jo) = o;
    }
}

// ---------------- GEMM2 via MFMA (mirrors gemm1m): x(f32->bf16 split) @ Bo.
// 48 cols = 40 Wh2 + s2s (col 40) + s2d (col 41) + 6 pad.

__global__ __launch_bounds__(256) void k_gemm2m(const float* __restrict__ x,
                                                const __bf16* __restrict__ Boh,
                                                const __bf16* __restrict__ Bol,
                                                float* __restrict__ Wh2,
                                                float* __restrict__ s2s,
                                                float* __restrict__ s2d) {
    int t = threadIdx.x;
    int wv = t >> 6, l = t & 63;
    int l15 = l & 15, lg = l >> 4;
    int rowA = blockIdx.x * 64 + wv * 16 + l15;
    bool rok = rowA < N_;
    const float* xp = x + (size_t)rowA * 256 + lg * 8;

    f32x4 acc[3];
#pragma unroll
    for (int i = 0; i < 3; i++) acc[i] = (f32x4){0.f, 0.f, 0.f, 0.f};

    for (int kc = 0; kc < 8; kc++) {
        float va[8] = {0.f, 0.f, 0.f, 0.f, 0.f, 0.f, 0.f, 0.f};
        if (rok) {
            float4 p = *(const float4*)(xp + kc * 32);
            float4 q = *(const float4*)(xp + kc * 32 + 4);
            va[0] = p.x; va[1] = p.y; va[2] = p.z; va[3] = p.w;
            va[4] = q.x; va[5] = q.y; va[6] = q.z; va[7] = q.w;
        }
        bf16x8 ahi, alo;
#pragma unroll
        for (int j = 0; j < 8; j++) {
            __bf16 hi = (__bf16)va[j];
            ahi[j] = hi;
            alo[j] = (__bf16)(va[j] - (float)hi);
        }
        const __bf16* bph = Boh + ((size_t)kc * 48 + l15) * 32 + lg * 8;
        const __bf16* bpl = Bol + ((size_t)kc * 48 + l15) * 32 + lg * 8;
#pragma unroll
        for (int tt = 0; tt < 3; tt++) {
            bf16x8 bh = *(const bf16x8*)(bph + tt * 512);
            bf16x8 bl = *(const bf16x8*)(bpl + tt * 512);
            acc[tt] = __builtin_amdgcn_mfma_f32_16x16x32_bf16(ahi, bh, acc[tt], 0, 0, 0);
            acc[tt] = __builtin_amdgcn_mfma_f32_16x16x32_bf16(alo, bh, acc[tt], 0, 0, 0);
            acc[tt] = __builtin_amdgcn_mfma_f32_16x16x32_bf16(ahi, bl, acc[tt], 0, 0, 0);
        }
    }

    int rowD0 = blockIdx.x * 64 + wv * 16 + lg * 4;
#pragma unroll
    for (int tt = 0; tt < 3; tt++) {
        int col = tt * 16 + l15;
#pragma unroll
        for (int r = 0; r < 4; r++) {
            int orow = rowD0 + r;
            if (orow < N_) {
                if (col < 40) Wh2[(size_t)orow * 40 + col] = acc[tt][r];
                else if (col == 40) s2s[orow] = acc[tt][r];
                else if (col == 41) s2d[orow] = acc[tt][r];
            }
        }
    }
}

// ---------------- layer-2: att2 inline; 8-edge x 8-lane class-interleave ----------------

__global__ __launch_bounds__(256) void k_l2(const int* __restrict__ rowptr, const int* __restrict__ csr,
                                            const float* __restrict__ s2s, const float* __restrict__ s2d,
                                            const float* __restrict__ Wh2, float* __restrict__ out) {
    int t = threadIdx.x;
    int wv = t >> 6, lane = t & 63;
    int n = blockIdx.x * 4 + wv;
    int base = rowptr[n], deg = rowptr[n + 1] - base;
    float sdw = s2d[n];

    // pass 1: max over edges (64-way)
    float mx = -INFINITY;
    for (int i = lane; i < deg; i += 64) {
        int s = csr[base + i];
        float e = s2s[s] + sdw;
        e = e > 0.f ? e : ALPHA * e;
        mx = fmaxf(mx, e);
    }
    for (int o = 32; o; o >>= 1) mx = fmaxf(mx, __shfl_xor(mx, o));

    // pass 2: 8 edges in flight; lane accumulates classes c8+8q
    int e8 = lane >> 3, c8 = lane & 7;
    float acc0 = 0.f, acc1 = 0.f, acc2 = 0.f, acc3 = 0.f, acc4 = 0.f;
    float smp = 0.f;
    for (int i = e8; i < deg; i += 8) {
        int s = csr[base + i];
        float e = s2s[s] + sdw;
        e = e > 0.f ? e : ALPHA * e;
        float a = expf(e - mx);
        smp += a;
        const float* wp = Wh2 + (size_t)s * 40 + c8;
        acc0 += a * wp[0];
        acc1 += a * wp[8];
        acc2 += a * wp[16];
        acc3 += a * wp[24];
        acc4 += a * wp[32];
    }
    for (int o = 8; o < 64; o <<= 1) {
        smp += __shfl_xor(smp, o);
        acc0 += __shfl_xor(acc0, o);
        acc1 += __shfl_xor(acc1, o);
        acc2 += __shfl_xor(acc2, o);
        acc3 += __shfl_xor(acc3, o);
        acc4 += __shfl_xor(acc4, o);
    }
    float inv = (deg > 0) ? 1.f / smp : 0.f;
    acc0 *= inv; acc1 *= inv; acc2 *= inv; acc3 *= inv; acc4 *= inv;

    // log_softmax over 40 classes (reduce across c8: masks 1,2,4)
    float mv = fmaxf(fmaxf(fmaxf(acc0, acc1), fmaxf(acc2, acc3)), acc4);
    for (int o = 1; o < 8; o <<= 1) mv = fmaxf(mv, __shfl_xor(mv, o));
    float se = expf(acc0 - mv) + expf(acc1 - mv) + expf(acc2 - mv) +
               expf(acc3 - mv) + expf(acc4 - mv);
    for (int o = 1; o < 8; o <<= 1) se += __shfl_xor(se, o);
    float lse = logf(se);
    if (e8 == 0) {
        float* op = out + (size_t)n * 40 + c8;
        op[0]  = acc0 - mv - lse;
        op[8]  = acc1 - mv - lse;
        op[16] = acc2 - mv - lse;
        op[24] = acc3 - mv - lse;
        op[32] = acc4 - mv - lse;
    }
}

// ---------------- host ----------------

extern "C" void kernel_launch(void* const* d_in, const int* in_sizes, int n_in,
                              void* d_out, int out_size, void* d_ws, size_t ws_size,
                              hipStream_t stream) {
    const float* h   = (const float*)d_in[0];
    const int*   ei  = (const int*)d_in[1];
    const float* Whd = (const float*)d_in[2];
    const float* ah  = (const float*)d_in[3];
    const float* Wo  = (const float*)d_in[4];
    const float* ao  = (const float*)d_in[5];
    float* out = (float*)d_out;

    const int* src = ei;
    const int* dst = ei + E_;
    const int nchunks = (N_ + 1023) / 1024;

    char* ws = (char*)d_ws;
    size_t off = 0;
    auto alloc = [&](size_t bytes) -> char* {
        size_t a = (off + 255) & ~(size_t)255;
        off = a + bytes;
        return ws + a;
    };
    int* rowptr = (int*)alloc((size_t)(N_ + 1) * 4);
    int* cursor = (int*)alloc((size_t)N_ * 4);
    int* deg    = (int*)alloc((size_t)N_ * 4);
    int* part   = (int*)alloc((size_t)(nchunks + 1) * 4);
    int* csr    = (int*)alloc((size_t)E_ * 4);
    float* s1s  = (float*)alloc((size_t)N_ * 4 * 4);
    float* s1d  = (float*)alloc((size_t)N_ * 4 * 4);
    float* sinv1= (float*)alloc((size_t)N_ * 4 * 4);
    float* Wh2  = (float*)alloc((size_t)N_ * 40 * 4);
    float* s2s  = (float*)alloc((size_t)N_ * 4);
    float* s2d  = (float*)alloc((size_t)N_ * 4);
    __bf16* Bh  = (__bf16*)alloc((size_t)8 * 272 * 32 * 2);   // 136 KB
    __bf16* Bl  = (__bf16*)alloc((size_t)8 * 272 * 32 * 2);
    __bf16* Boh = (__bf16*)alloc((size_t)8 * 48 * 32 * 2);    // 24.6 KB
    __bf16* Bol = (__bf16*)alloc((size_t)8 * 48 * 32 * 2);
    float* att1 = (float*)alloc((size_t)E_ * 4 * 4);               // 25.6 MB
    unsigned short* Wh1h = (unsigned short*)alloc((size_t)N_ * 256 * 2); // 51.2 MB
    float* x    = (float*)alloc((size_t)N_ * 256 * 4);             // 102.4 MB
    size_t need = off + 256;                                        // ~208 MB total

    if (ws_size < need) {
        k_sent<<<(int)((OUTEL + 255) / 256), 256, 0, stream>>>(out, OUTEL, -2.0f);
        return;
    }

    // B preps (independent of CSR)
    k_prepB<<<256, 320, 0, stream>>>(Whd, ah, Bh, Bl);
    k_prepB2<<<256, 64, 0, stream>>>(Wo, ao, Boh, Bol);

    // CSR build
    k_zero<<<(N_ + 255) / 256, 256, 0, stream>>>(deg, N_);
    k_count<<<(E_ + 255) / 256, 256, 0, stream>>>(dst, deg);
    k_partial<<<nchunks, 256, 0, stream>>>(deg, part);
    k_scan_part<<<1, 128, 0, stream>>>(part, nchunks, rowptr);
    k_scan_final<<<nchunks, 256, 0, stream>>>(deg, part, rowptr, cursor);
    k_fill<<<(E_ + 255) / 256, 256, 0, stream>>>(src, dst, cursor, csr);

    // layer 1: MFMA GEMM (fp16 Wh1 + f32 s1 scores), att1 (2 passes)
    k_gemm1m<<<(N_ + 63) / 64, 256, 0, stream>>>(h, Bh, Bl, Wh1h, s1s, s1d);
    k_att1<<<N_ / 4, 256, 0, stream>>>(rowptr, csr, s1s, s1d, att1, sinv1);

    // pure gather aggregate -> x (f32)
    k_agg1g<<<AGG_BLOCKS, 1024, 0, stream>>>(rowptr, csr, att1, sinv1, Wh1h, x);

    // GEMM2 via MFMA (Wh2 + s2 scores folded as B-columns)
    k_gemm2m<<<(N_ + 63) / 64, 256, 0, stream>>>(x, Boh, Bol, Wh2, s2s, s2d);

    // layer 2 (att2 + denominator fused; 8-edge ILP, coalesced Wh2 reads)
    k_l2<<<N_ / 4, 256, 0, stream>>>(rowptr, csr, s2s, s2d, Wh2, out);
}